// Round 10
// baseline (1124.093 us; speedup 1.0000x reference)
//
#include <hip/hip_runtime.h>
#include <hip/hip_cooperative_groups.h>
namespace cg = cooperative_groups;

static constexpr int BATCH = 16;
static constexpr int NNODE = 4096;
static constexpr int NEDGE = 65536;            // 1 << 16
static constexpr int ROWS  = BATCH * NNODE;    // 65536
static constexpr int CAP   = 2432;             // compacted slots/batch (76*32)
static constexpr int PM    = BATCH * CAP;
static constexpr int DCAP  = 64;               // per-node edge-bucket capacity
static constexpr int GRID  = 1280;             // 5 blocks/CU cooperative grid

typedef _Float16 half8  __attribute__((ext_vector_type(8)));
typedef _Float16 half4v __attribute__((ext_vector_type(4)));
typedef _Float16 half2v __attribute__((ext_vector_type(2)));
typedef float    f32x4  __attribute__((ext_vector_type(4)));
typedef float    f32x2  __attribute__((ext_vector_type(2)));

#define GP(p) (const __attribute__((address_space(1))) void*)(p)
#define LP(p) (__attribute__((address_space(3))) void*)(p)

// ===================== MEGA KERNEL (cooperative, 7 phases) ==================
// All round-9-verified bodies, grid-strided. grid.sync() between phases
// replaces 6 dispatch boundaries + the cursor memset.
__global__ __launch_bounds__(256, 5) void mega_kernel(
    const float* __restrict__ x, const int* __restrict__ ei,
    const float* __restrict__ ew, const int* __restrict__ mask,
    const float* __restrict__ W1, const float* __restrict__ b1,
    const float* __restrict__ W2, const float* __restrict__ b2,
    const float* __restrict__ W3, const float* __restrict__ b3,
    float* __restrict__ out,
    _Float16* __restrict__ Ac, _Float16* __restrict__ H3,
    unsigned int* __restrict__ bkt, _Float16* __restrict__ AggX,
    _Float16* __restrict__ AggA, _Float16* __restrict__ Wt1,
    _Float16* __restrict__ Wt2, _Float16* __restrict__ Wt3,
    int* __restrict__ cursor, int* __restrict__ vlist,
    int* __restrict__ validN)
{
    cg::grid_group grid = cg::this_grid();
    __shared__ _Float16 A16[8192];     // 16 KB (gemm panels / restage)
    __shared__ int sums[256];
    __shared__ int s_v[64];

    const int tid  = threadIdx.x;
    const int bx   = blockIdx.x;
    const int lane = tid & 63;
    const int wave = tid >> 6;
    const int quad = lane >> 4;
    const int l15  = lane & 15;

    // ---- phase 0: zero degree cursors ----
    {
        const int i = bx * 256 + tid;
        if (i < ROWS) cursor[i] = 0;
    }
    grid.sync();

    // ---- phase 1: build (edges -> buckets | W casts | compaction) ----
    for (int vb = bx; vb < 4624; vb += GRID) {
        if (vb < 4096) {
            const int idx = vb * 256 + tid;
            const int b = idx >> 16;
            const int e = idx & (NEDGE - 1);
            const int* eib = ei + (size_t)b * 2 * NEDGE;
            const int u = eib[e];
            const int v = eib[NEDGE + e];
            const int mrow = b * NNODE;
            if (mask[mrow + u] != 0 && mask[mrow + v] != 0) {
                const _Float16 w = (_Float16)ew[(size_t)b * NEDGE + e];
                const unsigned short wb = __builtin_bit_cast(unsigned short, w);
                const int pos = atomicAdd(&cursor[mrow + v], 1);
                if (pos < DCAP)
                    bkt[(size_t)(mrow + v) * DCAP + pos] = ((unsigned)wb << 16) | (unsigned)u;
            }
        } else if (vb < 4608) {
            const int i = (vb - 4096) * 256 + tid;
            if (i < 32768) {
                int k = i >> 8, n = i & 255;
                Wt1[n * 128 + k] = (_Float16)W1[i];
            } else if (i < 98304) {
                int j = i - 32768;
                int k = j >> 8, n = j & 255;
                Wt2[n * 256 + k] = (_Float16)W2[j];
            } else {
                int j = i - 98304;
                int k = j >> 7, n = j & 127;
                Wt3[n * 256 + k] = (_Float16)W3[j];
            }
        } else {
            const int b = vb - 4608;
            const int* mb = mask + b * NNODE;
            for (int i = tid; i < CAP; i += 256) vlist[b * CAP + i] = 0;

            int loc[16]; int s = 0;
            #pragma unroll
            for (int i = 0; i < 16; ++i) { loc[i] = (mb[tid * 16 + i] != 0); s += loc[i]; }
            sums[tid] = s;
            __syncthreads();
            for (int off = 1; off < 256; off <<= 1) {
                int v = (tid >= off) ? sums[tid - off] : 0;
                __syncthreads();
                sums[tid] += v;
                __syncthreads();
            }
            int run = (tid == 0) ? 0 : sums[tid - 1];
            #pragma unroll
            for (int i = 0; i < 16; ++i) {
                const int n = tid * 16 + i;
                if (loc[i]) {
                    if (run < CAP) vlist[b * CAP + run] = n;
                    ++run;
                }
            }
            if (tid == 255) validN[b] = run;
        }
    }
    grid.sync();

    // ---- phase 2: gather_x (agg of f32 x, 1 slot/wave) ----
    for (int vb = bx; vb < 9728; vb += GRID) {
        constexpr int NU = CAP / 4;            // 608
        const int xcd  = vb & 7;
        const int jj   = vb >> 3;
        const int batch = 2 * xcd + (jj >= NU);
        const int unit  = (jj >= NU) ? jj - NU : jj;
        const int j = unit * 4 + wave;
        if (j >= validN[batch]) continue;
        const int mrow = batch * NNODE;
        const int v = vlist[batch * CAP + j];
        int deg = cursor[mrow + v];
        deg = deg > DCAP ? DCAP : deg;
        const unsigned* bk = bkt + (size_t)(mrow + v) * DCAP;
        const float* Xb = x + (size_t)mrow * 128 + lane * 2;

        float a0 = 0.0f, a1 = 0.0f;
        for (int i = 0; i < deg; i += 8) {
            const int cnt = deg - i;
            unsigned pk[8];
            #pragma unroll
            for (int t = 0; t < 8; ++t) pk[t] = bk[i + t];
            float wj[8]; float2 xv[8];
            #pragma unroll
            for (int t = 0; t < 8; ++t) {
                const bool ok = (t < cnt);
                const unsigned u = pk[t] & 0xFFFu;
                wj[t] = ok ? (float)__builtin_bit_cast(_Float16, (unsigned short)(pk[t] >> 16)) : 0.0f;
                xv[t] = *(const float2*)(Xb + (size_t)u * 128);
            }
            #pragma unroll
            for (int t = 0; t < 8; ++t) { a0 += wj[t] * xv[t].x; a1 += wj[t] * xv[t].y; }
        }
        half2v o = {(_Float16)a0, (_Float16)a1};
        *(half2v*)&AggX[(size_t)(batch * CAP + j) * 128 + lane * 2] = o;
    }
    grid.sync();

    // ---- phase 3: gemm1 (AggX @ W1 + b1, relu, scatter Ac) — 32-row tiles --
    for (int vb = bx; vb < 1216; vb += GRID) {   // single iteration
        constexpr int NCH = CAP / 32;            // 76
        const int xcd  = vb & 7;
        const int j    = vb >> 3;
        const int batch = 2 * xcd + (j >= NCH);
        const int tile  = (j >= NCH) ? j - NCH : j;
        const int vN   = validN[batch];
        if (tile * 32 >= vN) continue;           // block-uniform
        const int mrow = batch * NNODE;
        const size_t bm = (size_t)batch * CAP + (size_t)tile * 32;

        if (tid < 32) {
            const int slot = tile * 32 + tid;
            s_v[tid] = (slot < vN) ? vlist[batch * CAP + slot] : 0;
        }
        const int half = tid >> 7;
        const int t7   = tid & 127;
        const int srow = t7 >> 2;                // 0..31
        const int sch  = (t7 & 3) * 8;
        #pragma unroll
        for (int ppp = 0; ppp < 2; ++ppp) {
            const int pp = 2 * ppp + half;
            __builtin_amdgcn_global_load_lds(
                GP(AggX + (bm + srow) * 128 + pp * 32 + sch),
                LP(A16 + pp * 1024 + t7 * 8), 16, 0, 0);
        }
        __syncthreads();

        f32x4 acc[2][4];
        #pragma unroll
        for (int mi = 0; mi < 2; ++mi)
            #pragma unroll
            for (int ni = 0; ni < 4; ++ni) acc[mi][ni] = (f32x4)0.0f;

        const _Float16* ap = A16 + l15 * 32 + quad * 8;
        const _Float16* wp = Wt1 + (size_t)(wave * 64 + l15) * 128 + quad * 8;
        #pragma unroll
        for (int pp = 0; pp < 4; ++pp) {
            half8 af[2], bf[4];
            #pragma unroll
            for (int mi = 0; mi < 2; ++mi)
                af[mi] = *(const half8*)(ap + pp * 1024 + mi * 512);
            #pragma unroll
            for (int ni = 0; ni < 4; ++ni)
                bf[ni] = *(const half8*)(wp + (size_t)ni * 16 * 128 + pp * 32);
            #pragma unroll
            for (int mi = 0; mi < 2; ++mi)
                #pragma unroll
                for (int ni = 0; ni < 4; ++ni)
                    acc[mi][ni] = __builtin_amdgcn_mfma_f32_16x16x32_f16(
                        bf[ni], af[mi], acc[mi][ni], 0, 0, 0);   // swapped
        }
        __syncthreads();   // A16 free for restage

        constexpr int RST = 72;
        _Float16* stg = A16 + wave * 16 * RST;
        const int rr = lane >> 2;
        const int c0 = lane & 3;
        #pragma unroll
        for (int mi = 0; mi < 2; ++mi) {
            #pragma unroll
            for (int ni = 0; ni < 4; ++ni) {
                f32x4 v = acc[mi][ni];
                const f32x4 bv = *(const f32x4*)&b1[wave * 64 + ni * 16 + quad * 4];
                half4v o;
                #pragma unroll
                for (int r = 0; r < 4; ++r) o[r] = (_Float16)fmaxf(v[r] + bv[r], 0.0f);
                *(half4v*)&stg[l15 * RST + ni * 16 + quad * 4] = o;
            }
            const int slot = tile * 32 + mi * 16 + rr;
            if (slot < vN) {
                const int vs = s_v[mi * 16 + rr];
                _Float16* hp2 = &Ac[((size_t)mrow + vs) * 256 + wave * 64];
                #pragma unroll
                for (int c = 0; c < 2; ++c) {
                    const int ch = (c0 + 4 * c) * 8;
                    half8 v = *(const half8*)&stg[rr * RST + ch];
                    *(half8*)(hp2 + ch) = v;
                }
            }
        }
    }
    grid.sync();

    // ---- phase 4: gather_agg (agg of Ac, 1 slot/wave) ----
    for (int vb = bx; vb < 9728; vb += GRID) {
        constexpr int NU = CAP / 4;
        const int xcd  = vb & 7;
        const int jj   = vb >> 3;
        const int batch = 2 * xcd + (jj >= NU);
        const int unit  = (jj >= NU) ? jj - NU : jj;
        const int j = unit * 4 + wave;
        if (j >= validN[batch]) continue;
        const int mrow = batch * NNODE;
        const int v = vlist[batch * CAP + j];
        int deg = cursor[mrow + v];
        deg = deg > DCAP ? DCAP : deg;
        const unsigned* bk = bkt + (size_t)(mrow + v) * DCAP;
        const _Float16* Ab = Ac + (size_t)mrow * 256 + lane * 4;

        float a0 = 0.0f, a1 = 0.0f, a2 = 0.0f, a3 = 0.0f;
        for (int i = 0; i < deg; i += 8) {
            const int cnt = deg - i;
            unsigned pk[8];
            #pragma unroll
            for (int t = 0; t < 8; ++t) pk[t] = bk[i + t];
            float wj[8]; half4v hv[8];
            #pragma unroll
            for (int t = 0; t < 8; ++t) {
                const bool ok = (t < cnt);
                const unsigned u = pk[t] & 0xFFFu;
                wj[t] = ok ? (float)__builtin_bit_cast(_Float16, (unsigned short)(pk[t] >> 16)) : 0.0f;
                hv[t] = *(const half4v*)(Ab + (size_t)u * 256);
            }
            #pragma unroll
            for (int t = 0; t < 8; ++t) {
                a0 += wj[t] * (float)hv[t][0];
                a1 += wj[t] * (float)hv[t][1];
                a2 += wj[t] * (float)hv[t][2];
                a3 += wj[t] * (float)hv[t][3];
            }
        }
        half4v o = {(_Float16)a0, (_Float16)a1, (_Float16)a2, (_Float16)a3};
        *(half4v*)&AggA[(size_t)(batch * CAP + j) * 256 + lane * 4] = o;
    }
    grid.sync();

    // ---- phase 5: gemm23 (AggA @ W2 + b2, relu, @ W3, scatter H3) ----------
    for (int vb = bx; vb < 1216; vb += GRID) {   // single iteration
        constexpr int NCH = CAP / 32;            // 76
        const int xcd  = vb & 7;
        const int j    = vb >> 3;
        const int batch = 2 * xcd + (j >= NCH);
        const int tile  = (j >= NCH) ? j - NCH : j;
        const int vN   = validN[batch];
        if (tile * 32 >= vN) continue;
        const int mrow = batch * NNODE;
        const size_t bm = (size_t)batch * CAP + (size_t)tile * 32;

        if (tid < 32) {
            const int slot = tile * 32 + tid;
            s_v[tid] = (slot < vN) ? vlist[batch * CAP + slot] : 0;
        }
        const int half = tid >> 7;
        const int t7   = tid & 127;
        const int srow = t7 >> 2;
        const int sch  = (t7 & 3) * 8;
        #pragma unroll
        for (int ppp = 0; ppp < 4; ++ppp) {
            const int pp = 2 * ppp + half;
            __builtin_amdgcn_global_load_lds(
                GP(AggA + (bm + srow) * 256 + pp * 32 + sch),
                LP(A16 + pp * 1024 + t7 * 8), 16, 0, 0);
        }
        __syncthreads();

        // phase-1 matmul: W2 (64 cols/wave, ni<4; M=32, mi<2)
        f32x4 acc[2][4];
        #pragma unroll
        for (int mi = 0; mi < 2; ++mi)
            #pragma unroll
            for (int ni = 0; ni < 4; ++ni) acc[mi][ni] = (f32x4)0.0f;

        const _Float16* ap = A16 + l15 * 32 + quad * 8;
        const _Float16* wp = Wt2 + (size_t)(wave * 64 + l15) * 256 + quad * 8;
        #pragma unroll
        for (int pp = 0; pp < 8; ++pp) {
            half8 af[2], bf[4];
            #pragma unroll
            for (int mi = 0; mi < 2; ++mi)
                af[mi] = *(const half8*)(ap + pp * 1024 + mi * 512);
            #pragma unroll
            for (int ni = 0; ni < 4; ++ni)
                bf[ni] = *(const half8*)(wp + (size_t)ni * 16 * 256 + pp * 32);
            #pragma unroll
            for (int mi = 0; mi < 2; ++mi)
                #pragma unroll
                for (int ni = 0; ni < 4; ++ni)
                    acc[mi][ni] = __builtin_amdgcn_mfma_f32_16x16x32_f16(
                        bf[ni], af[mi], acc[mi][ni], 0, 0, 0);
        }
        __syncthreads();

        // epilogue 1: relu(acc + b2) -> A16 panel layout [pp][row<32][32]
        #pragma unroll
        for (int mi = 0; mi < 2; ++mi) {
            const int row = mi * 16 + l15;
            #pragma unroll
            for (int ni = 0; ni < 4; ++ni) {
                const int col = wave * 64 + ni * 16 + quad * 4;
                const f32x4 bv = *(const f32x4*)&b2[col];
                f32x4 v = acc[mi][ni];
                half4v o;
                #pragma unroll
                for (int r = 0; r < 4; ++r) o[r] = (_Float16)fmaxf(v[r] + bv[r], 0.0f);
                *(half4v*)&A16[(col >> 5) * 1024 + row * 32 + (col & 31)] = o;
            }
        }
        __syncthreads();

        // phase-2 matmul: W3 (32 cols/wave, ni<2)
        f32x4 acc2[2][2];
        #pragma unroll
        for (int mi = 0; mi < 2; ++mi)
            #pragma unroll
            for (int ni = 0; ni < 2; ++ni) acc2[mi][ni] = (f32x4)0.0f;

        const _Float16* wp3 = Wt3 + (size_t)(wave * 32 + l15) * 256 + quad * 8;
        #pragma unroll
        for (int pp = 0; pp < 8; ++pp) {
            half8 af[2], bf[2];
            #pragma unroll
            for (int mi = 0; mi < 2; ++mi)
                af[mi] = *(const half8*)(ap + pp * 1024 + mi * 512);
            #pragma unroll
            for (int ni = 0; ni < 2; ++ni)
                bf[ni] = *(const half8*)(wp3 + (size_t)ni * 16 * 256 + pp * 32);
            #pragma unroll
            for (int mi = 0; mi < 2; ++mi)
                #pragma unroll
                for (int ni = 0; ni < 2; ++ni)
                    acc2[mi][ni] = __builtin_amdgcn_mfma_f32_16x16x32_f16(
                        bf[ni], af[mi], acc2[mi][ni], 0, 0, 0);
        }
        __syncthreads();   // A16 free for restage

        constexpr int RST = 40;
        _Float16* stg = A16 + wave * 16 * RST;
        const int rr = lane >> 2;
        const int c0 = lane & 3;
        #pragma unroll
        for (int mi = 0; mi < 2; ++mi) {
            #pragma unroll
            for (int ni = 0; ni < 2; ++ni) {
                f32x4 v = acc2[mi][ni];
                half4v o;
                #pragma unroll
                for (int r = 0; r < 4; ++r) o[r] = (_Float16)v[r];
                *(half4v*)&stg[l15 * RST + ni * 16 + quad * 4] = o;
            }
            const int slot = tile * 32 + mi * 16 + rr;
            if (slot < vN) {
                const int vs = s_v[mi * 16 + rr];
                _Float16* hp2 = &H3[((size_t)mrow + vs) * 128 + wave * 32];
                const int ch = c0 * 8;
                half8 v = *(const half8*)&stg[rr * RST + ch];
                *(half8*)(hp2 + ch) = v;
            }
        }
    }
    grid.sync();

    // ---- phase 6: gather_final (agg H3 + b3 + relu + mask) ----
    for (int vb = bx; vb < 16384; vb += GRID) {
        constexpr int NU = NNODE / 4;           // 1024
        const int xcd  = vb & 7;
        const int jj   = vb >> 3;
        const int batch = 2 * xcd + (jj >= NU);
        const int unit  = (jj >= NU) ? jj - NU : jj;
        const int n = unit * 4 + wave;
        const int mrow = batch * NNODE + n;

        float acc[2] = {};
        if (mask[mrow] != 0) {
            int deg = cursor[mrow];
            deg = deg > DCAP ? DCAP : deg;
            const unsigned* bk = bkt + (size_t)mrow * DCAP;
            const _Float16* Hb = H3 + (size_t)batch * NNODE * 128 + lane * 2;

            for (int i = 0; i < deg; i += 8) {
                const int cnt = deg - i;
                unsigned pk[8];
                #pragma unroll
                for (int t = 0; t < 8; ++t) pk[t] = bk[i + t];
                float wj[8]; const _Float16* hp[8];
                #pragma unroll
                for (int t = 0; t < 8; ++t) {
                    const bool ok = (t < cnt);
                    const unsigned u = pk[t] & 0xFFFu;
                    wj[t] = ok ? (float)__builtin_bit_cast(_Float16, (unsigned short)(pk[t] >> 16)) : 0.0f;
                    hp[t] = Hb + (size_t)u * 128;
                }
                half2v hv[8];
                #pragma unroll
                for (int t = 0; t < 8; ++t) hv[t] = *(const half2v*)hp[t];
                #pragma unroll
                for (int t = 0; t < 8; ++t)
                    #pragma unroll
                    for (int c = 0; c < 2; ++c) acc[c] += wj[t] * (float)hv[t][c];
            }
            #pragma unroll
            for (int c = 0; c < 2; ++c)
                acc[c] = fmaxf(acc[c] + b3[lane * 2 + c], 0.0f);
        }
        f32x2 o = {acc[0], acc[1]};
        *(f32x2*)&out[(size_t)mrow * 128 + lane * 2] = o;
    }
}

// ===================== FALLBACK: round-9 verified 7-dispatch path ===========

__global__ __launch_bounds__(256) void build_kernel(
    const int* __restrict__ ei, const float* __restrict__ ew,
    const int* __restrict__ mask,
    const float* __restrict__ W1, const float* __restrict__ W2,
    const float* __restrict__ W3,
    int* __restrict__ cursor, unsigned int* __restrict__ bkt,
    _Float16* __restrict__ Wt1, _Float16* __restrict__ Wt2,
    _Float16* __restrict__ Wt3,
    int* __restrict__ vlist, int* __restrict__ validN)
{
    __shared__ int sums[256];
    const int blk = blockIdx.x;
    const int t   = threadIdx.x;

    if (blk < 4096) {
        const int idx = blk * 256 + t;
        const int b = idx >> 16;
        const int e = idx & (NEDGE - 1);
        const int* eib = ei + (size_t)b * 2 * NEDGE;
        const int u = eib[e];
        const int v = eib[NEDGE + e];
        const int mrow = b * NNODE;
        if (mask[mrow + u] != 0 && mask[mrow + v] != 0) {
            const _Float16 w = (_Float16)ew[(size_t)b * NEDGE + e];
            const unsigned short wb = __builtin_bit_cast(unsigned short, w);
            const int pos = atomicAdd(&cursor[mrow + v], 1);
            if (pos < DCAP)
                bkt[(size_t)(mrow + v) * DCAP + pos] = ((unsigned)wb << 16) | (unsigned)u;
        }
    } else if (blk < 4608) {
        const int i = (blk - 4096) * 256 + t;
        if (i < 32768) {
            int k = i >> 8, n = i & 255;
            Wt1[n * 128 + k] = (_Float16)W1[i];
        } else if (i < 98304) {
            int j = i - 32768;
            int k = j >> 8, n = j & 255;
            Wt2[n * 256 + k] = (_Float16)W2[j];
        } else {
            int j = i - 98304;
            int k = j >> 7, n = j & 127;
            Wt3[n * 256 + k] = (_Float16)W3[j];
        }
    } else {
        const int b = blk - 4608;
        const int* mb = mask + b * NNODE;
        for (int i = t; i < CAP; i += 256) vlist[b * CAP + i] = 0;

        int loc[16]; int s = 0;
        #pragma unroll
        for (int i = 0; i < 16; ++i) { loc[i] = (mb[t * 16 + i] != 0); s += loc[i]; }
        sums[t] = s;
        __syncthreads();
        for (int off = 1; off < 256; off <<= 1) {
            int v = (t >= off) ? sums[t - off] : 0;
            __syncthreads();
            sums[t] += v;
            __syncthreads();
        }
        int run = (t == 0) ? 0 : sums[t - 1];
        #pragma unroll
        for (int i = 0; i < 16; ++i) {
            const int n = t * 16 + i;
            if (loc[i]) {
                if (run < CAP) vlist[b * CAP + run] = n;
                ++run;
            }
        }
        if (t == 255) validN[b] = run;
    }
}

__global__ __launch_bounds__(256) void gather_x(
    const int* __restrict__ cursor, const unsigned int* __restrict__ bkt,
    const float* __restrict__ X, const int* __restrict__ vlist,
    const int* __restrict__ validN, _Float16* __restrict__ AggX)
{
    constexpr int NU = CAP / 4;
    const int lane = threadIdx.x & 63;
    const int wave = threadIdx.x >> 6;
    const int xcd  = blockIdx.x & 7;
    const int jj   = blockIdx.x >> 3;
    const int batch = 2 * xcd + (jj >= NU);
    const int unit  = (jj >= NU) ? jj - NU : jj;

    const int j = unit * 4 + wave;
    if (j >= validN[batch]) return;
    const int mrow = batch * NNODE;
    const int v = vlist[batch * CAP + j];
    int deg = cursor[mrow + v];
    deg = deg > DCAP ? DCAP : deg;
    const unsigned* bk = bkt + (size_t)(mrow + v) * DCAP;
    const float* Xb = X + (size_t)mrow * 128 + lane * 2;

    float a0 = 0.0f, a1 = 0.0f;
    for (int i = 0; i < deg; i += 8) {
        const int cnt = deg - i;
        unsigned pk[8];
        #pragma unroll
        for (int t = 0; t < 8; ++t) pk[t] = bk[i + t];
        float wj[8]; float2 xv[8];
        #pragma unroll
        for (int t = 0; t < 8; ++t) {
            const bool ok = (t < cnt);
            const unsigned u = pk[t] & 0xFFFu;
            wj[t] = ok ? (float)__builtin_bit_cast(_Float16, (unsigned short)(pk[t] >> 16)) : 0.0f;
            xv[t] = *(const float2*)(Xb + (size_t)u * 128);
        }
        #pragma unroll
        for (int t = 0; t < 8; ++t) { a0 += wj[t] * xv[t].x; a1 += wj[t] * xv[t].y; }
    }
    half2v o = {(_Float16)a0, (_Float16)a1};
    *(half2v*)&AggX[(size_t)(batch * CAP + j) * 128 + lane * 2] = o;
}

__global__ __launch_bounds__(256) void gather_agg(
    const int* __restrict__ cursor, const unsigned int* __restrict__ bkt,
    const _Float16* __restrict__ Ac, const int* __restrict__ vlist,
    const int* __restrict__ validN, _Float16* __restrict__ AggA)
{
    constexpr int NU = CAP / 4;
    const int lane = threadIdx.x & 63;
    const int wave = threadIdx.x >> 6;
    const int xcd  = blockIdx.x & 7;
    const int jj   = blockIdx.x >> 3;
    const int batch = 2 * xcd + (jj >= NU);
    const int unit  = (jj >= NU) ? jj - NU : jj;

    const int j = unit * 4 + wave;
    if (j >= validN[batch]) return;
    const int mrow = batch * NNODE;
    const int v = vlist[batch * CAP + j];
    int deg = cursor[mrow + v];
    deg = deg > DCAP ? DCAP : deg;
    const unsigned* bk = bkt + (size_t)(mrow + v) * DCAP;
    const _Float16* Ab = Ac + (size_t)mrow * 256 + lane * 4;

    float a0 = 0.0f, a1 = 0.0f, a2 = 0.0f, a3 = 0.0f;
    for (int i = 0; i < deg; i += 8) {
        const int cnt = deg - i;
        unsigned pk[8];
        #pragma unroll
        for (int t = 0; t < 8; ++t) pk[t] = bk[i + t];
        float wj[8]; half4v hv[8];
        #pragma unroll
        for (int t = 0; t < 8; ++t) {
            const bool ok = (t < cnt);
            const unsigned u = pk[t] & 0xFFFu;
            wj[t] = ok ? (float)__builtin_bit_cast(_Float16, (unsigned short)(pk[t] >> 16)) : 0.0f;
            hv[t] = *(const half4v*)(Ab + (size_t)u * 256);
        }
        #pragma unroll
        for (int t = 0; t < 8; ++t) {
            a0 += wj[t] * (float)hv[t][0];
            a1 += wj[t] * (float)hv[t][1];
            a2 += wj[t] * (float)hv[t][2];
            a3 += wj[t] * (float)hv[t][3];
        }
    }
    half4v o = {(_Float16)a0, (_Float16)a1, (_Float16)a2, (_Float16)a3};
    *(half4v*)&AggA[(size_t)(batch * CAP + j) * 256 + lane * 4] = o;
}

__global__ __launch_bounds__(256, 3) void gemm1_kernel(
    const _Float16* __restrict__ Xc, const int* __restrict__ vlist,
    const int* __restrict__ validN, const _Float16* __restrict__ Wt,
    const float* __restrict__ bias, _Float16* __restrict__ Ac)
{
    constexpr int K = 128, NW = 64, NI = 4, RST = 72;
    constexpr int NPAN = 4;
    constexpr int NCH  = CAP / 64;
    constexpr int ASZ  = (NPAN * 2048) > (4 * 16 * RST) ? (NPAN * 2048) : (4 * 16 * RST);
    __shared__ _Float16 A16[ASZ];
    __shared__ int s_v[64];

    const int tid  = threadIdx.x;
    const int lane = tid & 63;
    const int wave = tid >> 6;
    const int quad = lane >> 4;
    const int l15  = lane & 15;

    const int xcd  = blockIdx.x & 7;
    const int j    = blockIdx.x >> 3;
    const int batch = 2 * xcd + (j >= NCH);
    const int tile  = (j >= NCH) ? j - NCH : j;
    const int vN   = validN[batch];
    if (tile * 64 >= vN) return;
    const int mrow = batch * NNODE;
    const size_t bm = (size_t)batch * CAP + (size_t)tile * 64;

    if (tid < 64) {
        const int slot = tile * 64 + tid;
        s_v[tid] = (slot < vN) ? vlist[batch * CAP + slot] : 0;
    }
    const int srow = tid >> 2;
    const int sch  = (tid & 3) * 8;
    #pragma unroll
    for (int pp = 0; pp < NPAN; ++pp)
        __builtin_amdgcn_global_load_lds(
            GP(Xc + (bm + srow) * K + pp * 32 + sch),
            LP(A16 + pp * 2048 + tid * 8), 16, 0, 0);
    __syncthreads();

    f32x4 acc[4][NI];
    #pragma unroll
    for (int mi = 0; mi < 4; ++mi)
        #pragma unroll
        for (int ni = 0; ni < NI; ++ni) acc[mi][ni] = (f32x4)0.0f;

    const _Float16* ap = A16 + l15 * 32 + quad * 8;
    const _Float16* wp = Wt + (size_t)(wave * NW + l15) * K + quad * 8;

    #pragma unroll
    for (int pp = 0; pp < NPAN; ++pp) {
        half8 af[4], bf[NI];
        #pragma unroll
        for (int mi = 0; mi < 4; ++mi)
            af[mi] = *(const half8*)(ap + pp * 2048 + mi * 16 * 32);
        #pragma unroll
        for (int ni = 0; ni < NI; ++ni)
            bf[ni] = *(const half8*)(wp + (size_t)ni * 16 * K + pp * 32);
        #pragma unroll
        for (int mi = 0; mi < 4; ++mi)
            #pragma unroll
            for (int ni = 0; ni < NI; ++ni)
                acc[mi][ni] = __builtin_amdgcn_mfma_f32_16x16x32_f16(
                    bf[ni], af[mi], acc[mi][ni], 0, 0, 0);
    }
    __syncthreads();

    _Float16* stg = A16 + wave * 16 * RST;
    const int rr = lane >> 2;
    const int c0 = lane & 3;
    #pragma unroll
    for (int mi = 0; mi < 4; ++mi) {
        #pragma unroll
        for (int ni = 0; ni < NI; ++ni) {
            f32x4 v = acc[mi][ni];
            const f32x4 bv = *(const f32x4*)&bias[wave * NW + ni * 16 + quad * 4];
            half4v o;
            #pragma unroll
            for (int r = 0; r < 4; ++r) o[r] = (_Float16)fmaxf(v[r] + bv[r], 0.0f);
            *(half4v*)&stg[l15 * RST + ni * 16 + quad * 4] = o;
        }
        const int slot = tile * 64 + mi * 16 + rr;
        if (slot < vN) {
            const int vs = s_v[mi * 16 + rr];
            _Float16* hp2 = &Ac[((size_t)mrow + vs) * 256 + wave * NW];
            #pragma unroll
            for (int c = 0; c < NI / 2; ++c) {
                const int ch = (c0 + 4 * c) * 8;
                half8 v = *(const half8*)&stg[rr * RST + ch];
                *(half8*)(hp2 + ch) = v;
            }
        }
    }
}

__global__ __launch_bounds__(256, 3) void gemm23_kernel(
    const _Float16* __restrict__ Xc, const int* __restrict__ vlist,
    const int* __restrict__ validN, const _Float16* __restrict__ Wt2,
    const _Float16* __restrict__ Wt3, const float* __restrict__ b2,
    _Float16* __restrict__ H3)
{
    constexpr int K    = 256;
    constexpr int NPAN = 8;
    constexpr int NCH  = CAP / 64;
    __shared__ _Float16 A16[NPAN * 2048];
    __shared__ int s_v[64];

    const int tid  = threadIdx.x;
    const int lane = tid & 63;
    const int wave = tid >> 6;
    const int quad = lane >> 4;
    const int l15  = lane & 15;

    const int xcd  = blockIdx.x & 7;
    const int j    = blockIdx.x >> 3;
    const int batch = 2 * xcd + (j >= NCH);
    const int tile  = (j >= NCH) ? j - NCH : j;
    const int vN   = validN[batch];
    if (tile * 64 >= vN) return;
    const int mrow = batch * NNODE;
    const size_t bm = (size_t)batch * CAP + (size_t)tile * 64;

    if (tid < 64) {
        const int slot = tile * 64 + tid;
        s_v[tid] = (slot < vN) ? vlist[batch * CAP + slot] : 0;
    }
    const int srow = tid >> 2;
    const int sch  = (tid & 3) * 8;
    #pragma unroll
    for (int pp = 0; pp < NPAN; ++pp)
        __builtin_amdgcn_global_load_lds(
            GP(Xc + (bm + srow) * K + pp * 32 + sch),
            LP(A16 + pp * 2048 + tid * 8), 16, 0, 0);
    __syncthreads();

    f32x4 acc[4][4];
    #pragma unroll
    for (int mi = 0; mi < 4; ++mi)
        #pragma unroll
        for (int ni = 0; ni < 4; ++ni) acc[mi][ni] = (f32x4)0.0f;

    const _Float16* ap = A16 + l15 * 32 + quad * 8;
    const _Float16* wp = Wt2 + (size_t)(wave * 64 + l15) * K + quad * 8;

    #pragma unroll
    for (int pp = 0; pp < NPAN; ++pp) {
        half8 af[4], bf[4];
        #pragma unroll
        for (int mi = 0; mi < 4; ++mi)
            af[mi] = *(const half8*)(ap + pp * 2048 + mi * 16 * 32);
        #pragma unroll
        for (int ni = 0; ni < 4; ++ni)
            bf[ni] = *(const half8*)(wp + (size_t)ni * 16 * K + pp * 32);
        #pragma unroll
        for (int mi = 0; mi < 4; ++mi)
            #pragma unroll
            for (int ni = 0; ni < 4; ++ni)
                acc[mi][ni] = __builtin_amdgcn_mfma_f32_16x16x32_f16(
                    bf[ni], af[mi], acc[mi][ni], 0, 0, 0);
    }
    __syncthreads();

    #pragma unroll
    for (int mi = 0; mi < 4; ++mi) {
        const int row = mi * 16 + l15;
        #pragma unroll
        for (int ni = 0; ni < 4; ++ni) {
            const int col = wave * 64 + ni * 16 + quad * 4;
            const f32x4 bv = *(const f32x4*)&b2[col];
            f32x4 v = acc[mi][ni];
            half4v o;
            #pragma unroll
            for (int r = 0; r < 4; ++r) o[r] = (_Float16)fmaxf(v[r] + bv[r], 0.0f);
            *(half4v*)&A16[(col >> 5) * 2048 + row * 32 + (col & 31)] = o;
        }
    }
    __syncthreads();

    f32x4 acc2[4][2];
    #pragma unroll
    for (int mi = 0; mi < 4; ++mi)
        #pragma unroll
        for (int ni = 0; ni < 2; ++ni) acc2[mi][ni] = (f32x4)0.0f;

    const _Float16* wp3 = Wt3 + (size_t)(wave * 32 + l15) * K + quad * 8;
    #pragma unroll
    for (int pp = 0; pp < NPAN; ++pp) {
        half8 af[4], bf[2];
        #pragma unroll
        for (int mi = 0; mi < 4; ++mi)
            af[mi] = *(const half8*)(ap + pp * 2048 + mi * 16 * 32);
        #pragma unroll
        for (int ni = 0; ni < 2; ++ni)
            bf[ni] = *(const half8*)(wp3 + (size_t)ni * 16 * K + pp * 32);
        #pragma unroll
        for (int mi = 0; mi < 4; ++mi)
            #pragma unroll
            for (int ni = 0; ni < 2; ++ni)
                acc2[mi][ni] = __builtin_amdgcn_mfma_f32_16x16x32_f16(
                    bf[ni], af[mi], acc2[mi][ni], 0, 0, 0);
    }
    __syncthreads();

    constexpr int RST = 40;
    _Float16* stg = A16 + wave * 16 * RST;
    const int rr = lane >> 2;
    const int c0 = lane & 3;
    #pragma unroll
    for (int mi = 0; mi < 4; ++mi) {
        #pragma unroll
        for (int ni = 0; ni < 2; ++ni) {
            f32x4 v = acc2[mi][ni];
            half4v o;
            #pragma unroll
            for (int r = 0; r < 4; ++r) o[r] = (_Float16)v[r];
            *(half4v*)&stg[l15 * RST + ni * 16 + quad * 4] = o;
        }
        const int slot = tile * 64 + mi * 16 + rr;
        if (slot < vN) {
            const int vs = s_v[mi * 16 + rr];
            _Float16* hp2 = &H3[((size_t)mrow + vs) * 128 + wave * 32];
            const int ch = c0 * 8;
            half8 v = *(const half8*)&stg[rr * RST + ch];
            *(half8*)(hp2 + ch) = v;
        }
    }
}

__global__ __launch_bounds__(256) void gather_final(
    const int* __restrict__ cursor, const unsigned int* __restrict__ bkt,
    const _Float16* __restrict__ H3, const int* __restrict__ mask,
    const float* __restrict__ bias, float* __restrict__ OUT)
{
    constexpr int NU = NNODE / 4;
    const int lane = threadIdx.x & 63;
    const int wave = threadIdx.x >> 6;

    const int xcd  = blockIdx.x & 7;
    const int jj   = blockIdx.x >> 3;
    const int batch = 2 * xcd + (jj >= NU);
    const int unit  = (jj >= NU) ? jj - NU : jj;

    const int n = unit * 4 + wave;
    const int mrow = batch * NNODE + n;

    float acc[2] = {};
    if (mask[mrow] != 0) {
        int deg = cursor[mrow];
        deg = deg > DCAP ? DCAP : deg;
        const unsigned* bk = bkt + (size_t)mrow * DCAP;
        const _Float16* Hb = H3 + (size_t)batch * NNODE * 128 + lane * 2;

        for (int i = 0; i < deg; i += 8) {
            const int cnt = deg - i;
            unsigned pk[8];
            #pragma unroll
            for (int t = 0; t < 8; ++t) pk[t] = bk[i + t];
            float wj[8]; const _Float16* hp[8];
            #pragma unroll
            for (int t = 0; t < 8; ++t) {
                const bool ok = (t < cnt);
                const unsigned u = pk[t] & 0xFFFu;
                wj[t] = ok ? (float)__builtin_bit_cast(_Float16, (unsigned short)(pk[t] >> 16)) : 0.0f;
                hp[t] = Hb + (size_t)u * 128;
            }
            half2v hv[8];
            #pragma unroll
            for (int t = 0; t < 8; ++t) hv[t] = *(const half2v*)hp[t];
            #pragma unroll
            for (int t = 0; t < 8; ++t)
                #pragma unroll
                for (int c = 0; c < 2; ++c) acc[c] += wj[t] * (float)hv[t][c];
        }
        #pragma unroll
        for (int c = 0; c < 2; ++c)
            acc[c] = fmaxf(acc[c] + bias[lane * 2 + c], 0.0f);
    }
    f32x2 o = {acc[0], acc[1]};
    *(f32x2*)&OUT[(size_t)mrow * 128 + lane * 2] = o;
}

extern "C" void kernel_launch(void* const* d_in, const int* in_sizes, int n_in,
                              void* d_out, int out_size, void* d_ws, size_t ws_size,
                              hipStream_t stream) {
    const float* x    = (const float*)d_in[0];
    const int*   ei   = (const int*)  d_in[1];
    const float* ew   = (const float*)d_in[2];
    const int*   mask = (const int*)  d_in[3];
    const float* W1   = (const float*)d_in[4];
    const float* b1   = (const float*)d_in[5];
    const float* W2   = (const float*)d_in[6];
    const float* b2   = (const float*)d_in[7];
    const float* W3   = (const float*)d_in[8];
    const float* b3   = (const float*)d_in[9];
    float* out = (float*)d_out;

    // Workspace layout (~95 MB):
    char* ws = (char*)d_ws;
    _Float16* Ac   = (_Float16*)(ws);                      // 32 MB [ROWS,256] full
    _Float16* H3   = (_Float16*)(ws + (32u << 20));        // 16 MB [ROWS,128] full
    unsigned int* bkt = (unsigned int*)(ws + (48u << 20)); // 16 MB [ROWS,DCAP]
    _Float16* AggX = (_Float16*)(ws + (64u << 20));        // 10 MB [PM,128] compact
    _Float16* AggA = (_Float16*)(ws + (74u << 20));        // 20 MB [PM,256] compact
    _Float16* Wt1  = (_Float16*)(ws + (94u << 20));        // 64 KB
    _Float16* Wt2  = Wt1 + 128 * 256;                      // 128 KB
    _Float16* Wt3  = Wt2 + 256 * 256;                      // 64 KB
    int* cursor    = (int*)(Wt3 + 256 * 128);              // 256 KB (degrees)
    int* vlist     = cursor + ROWS;                        // 152 KB
    int* validN    = vlist + PM;

    const dim3 blk(256);

    // ---- preferred path: single cooperative dispatch ----
    void* args[] = {
        (void*)&x, (void*)&ei, (void*)&ew, (void*)&mask,
        (void*)&W1, (void*)&b1, (void*)&W2, (void*)&b2, (void*)&W3, (void*)&b3,
        (void*)&out,
        (void*)&Ac, (void*)&H3, (void*)&bkt, (void*)&AggX, (void*)&AggA,
        (void*)&Wt1, (void*)&Wt2, (void*)&Wt3,
        (void*)&cursor, (void*)&vlist, (void*)&validN };
    hipError_t err = hipLaunchCooperativeKernel(
        reinterpret_cast<void*>(mega_kernel), dim3(GRID), blk, args, 0, stream);
    if (err == hipSuccess) return;

    // ---- fallback: round-9 verified 7-dispatch pipeline ----
    hipMemsetAsync(cursor, 0, (size_t)ROWS * sizeof(int), stream);
    build_kernel<<<4624, blk, 0, stream>>>(ei, ew, mask, W1, W2, W3,
                                           cursor, bkt, Wt1, Wt2, Wt3,
                                           vlist, validN);
    const int gemmBlocks = PM / 64;
    const int aggBlocks  = PM / 4;
    const int finBlocks  = ROWS / 4;
    gather_x<<<aggBlocks, blk, 0, stream>>>(cursor, bkt, x, vlist, validN, AggX);
    gemm1_kernel<<<gemmBlocks, blk, 0, stream>>>(AggX, vlist, validN, Wt1, b1, Ac);
    gather_agg<<<aggBlocks, blk, 0, stream>>>(cursor, bkt, Ac, vlist, validN, AggA);
    gemm23_kernel<<<gemmBlocks, blk, 0, stream>>>(AggA, vlist, validN, Wt2, Wt3, b2, H3);
    gather_final<<<finBlocks, blk, 0, stream>>>(cursor, bkt, H3, mask, b3, out);
}

// Round 11
// 520.771 us; speedup vs baseline: 2.1585x; 2.1585x over previous
//
#include <hip/hip_runtime.h>
#include <hip/hip_cooperative_groups.h>
namespace cg = cooperative_groups;

static constexpr int BATCH = 16;
static constexpr int NNODE = 4096;
static constexpr int NEDGE = 65536;            // 1 << 16
static constexpr int ROWS  = BATCH * NNODE;    // 65536
static constexpr int CAP   = 2432;             // compacted slots/batch (38*64)
static constexpr int PM    = BATCH * CAP;
static constexpr int DCAP  = 64;               // per-node edge-bucket capacity
static constexpr int GRID_B = 2048;            // coop_build grid: 8 blocks/CU

typedef _Float16 half8  __attribute__((ext_vector_type(8)));
typedef _Float16 half4v __attribute__((ext_vector_type(4)));
typedef _Float16 half2v __attribute__((ext_vector_type(2)));
typedef float    f32x4  __attribute__((ext_vector_type(4)));
typedef float    f32x2  __attribute__((ext_vector_type(2)));

#define GP(p) (const __attribute__((address_space(1))) void*)(p)
#define LP(p) (__attribute__((address_space(3))) void*)(p)

// ================= coop_build: zero + build + gather_x (one dispatch) =======
// ONLY low-VGPR phases (all <= ~56 regs) share this kernel — round-10
// post-mortem: mixing MFMA phases into a cooperative kernel forced a 48-VGPR
// allocation and spilled GEMM accumulators to scratch (+90 MB HBM writes).
__global__ __launch_bounds__(256, 8) void coop_build(
    const int* __restrict__ ei, const float* __restrict__ ew,
    const int* __restrict__ mask, const float* __restrict__ X,
    const float* __restrict__ W1, const float* __restrict__ W2,
    const float* __restrict__ W3,
    int* __restrict__ cursor, unsigned int* __restrict__ bkt,
    _Float16* __restrict__ Wt1, _Float16* __restrict__ Wt2,
    _Float16* __restrict__ Wt3,
    int* __restrict__ vlist, int* __restrict__ validN,
    _Float16* __restrict__ AggX)
{
    cg::grid_group grid = cg::this_grid();
    __shared__ int sums[256];
    const int tid  = threadIdx.x;
    const int bx   = blockIdx.x;
    const int lane = tid & 63;
    const int wave = tid >> 6;

    // ---- phase 0: zero degree cursors (replaces hipMemsetAsync) ----
    {
        const int i = bx * 256 + tid;
        if (i < ROWS) cursor[i] = 0;
    }
    grid.sync();

    // ---- phase 1: build (edges -> buckets | W casts | compaction) ----
    for (int vb = bx; vb < 4624; vb += GRID_B) {
        if (vb < 4096) {
            // bkt entry = (fp16bits(w) << 16) | raw_u  (u < 4096 fits 12 bits)
            const int idx = vb * 256 + tid;
            const int b = idx >> 16;
            const int e = idx & (NEDGE - 1);
            const int* eib = ei + (size_t)b * 2 * NEDGE;
            const int u = eib[e];
            const int v = eib[NEDGE + e];
            const int mrow = b * NNODE;
            if (mask[mrow + u] != 0 && mask[mrow + v] != 0) {
                const _Float16 w = (_Float16)ew[(size_t)b * NEDGE + e];
                const unsigned short wb = __builtin_bit_cast(unsigned short, w);
                const int pos = atomicAdd(&cursor[mrow + v], 1);
                if (pos < DCAP)
                    bkt[(size_t)(mrow + v) * DCAP + pos] = ((unsigned)wb << 16) | (unsigned)u;
            }
        } else if (vb < 4608) {
            const int i = (vb - 4096) * 256 + tid;     // [0, 131072)
            if (i < 32768) {
                int k = i >> 8, n = i & 255;
                Wt1[n * 128 + k] = (_Float16)W1[i];
            } else if (i < 98304) {
                int j = i - 32768;
                int k = j >> 8, n = j & 255;
                Wt2[n * 256 + k] = (_Float16)W2[j];
            } else {
                int j = i - 98304;
                int k = j >> 7, n = j & 127;
                Wt3[n * 256 + k] = (_Float16)W3[j];
            }
        } else {
            // per-batch node compaction (block-uniform branch; syncthreads ok)
            const int b = vb - 4608;
            const int* mb = mask + b * NNODE;
            for (int i = tid; i < CAP; i += 256) vlist[b * CAP + i] = 0;

            int loc[16]; int s = 0;
            #pragma unroll
            for (int i = 0; i < 16; ++i) { loc[i] = (mb[tid * 16 + i] != 0); s += loc[i]; }
            sums[tid] = s;
            __syncthreads();
            for (int off = 1; off < 256; off <<= 1) {
                int v = (tid >= off) ? sums[tid - off] : 0;
                __syncthreads();
                sums[tid] += v;
                __syncthreads();
            }
            int run = (tid == 0) ? 0 : sums[tid - 1];
            #pragma unroll
            for (int i = 0; i < 16; ++i) {
                const int n = tid * 16 + i;
                if (loc[i]) {
                    if (run < CAP) vlist[b * CAP + run] = n;
                    ++run;
                }
            }
            if (tid == 255) validN[b] = run;
        }
    }
    grid.sync();

    // ---- phase 2: gather_x (agg of f32 x, 1 slot/wave) ----
    for (int vb = bx; vb < 9728; vb += GRID_B) {      // stride ≡ 0 mod 8
        constexpr int NU = CAP / 4;                   // 608
        const int xcd  = vb & 7;
        const int jj   = vb >> 3;
        const int batch = 2 * xcd + (jj >= NU);
        const int unit  = (jj >= NU) ? jj - NU : jj;
        const int j = unit * 4 + wave;
        if (j >= validN[batch]) continue;
        const int mrow = batch * NNODE;
        const int v = vlist[batch * CAP + j];
        int deg = cursor[mrow + v];
        deg = deg > DCAP ? DCAP : deg;
        const unsigned* bk = bkt + (size_t)(mrow + v) * DCAP;
        const float* Xb = X + (size_t)mrow * 128 + lane * 2;

        float a0 = 0.0f, a1 = 0.0f;
        for (int i = 0; i < deg; i += 8) {
            const int cnt = deg - i;
            unsigned pk[8];
            #pragma unroll
            for (int t = 0; t < 8; ++t) pk[t] = bk[i + t];
            float wj[8]; float2 xv[8];
            #pragma unroll
            for (int t = 0; t < 8; ++t) {
                const bool ok = (t < cnt);
                const unsigned u = pk[t] & 0xFFFu;
                wj[t] = ok ? (float)__builtin_bit_cast(_Float16, (unsigned short)(pk[t] >> 16)) : 0.0f;
                xv[t] = *(const float2*)(Xb + (size_t)u * 128);
            }
            #pragma unroll
            for (int t = 0; t < 8; ++t) { a0 += wj[t] * xv[t].x; a1 += wj[t] * xv[t].y; }
        }
        half2v o = {(_Float16)a0, (_Float16)a1};
        *(half2v*)&AggX[(size_t)(batch * CAP + j) * 128 + lane * 2] = o;
    }
}

// ===================== round-9 verified kernels (dispatches 2-5 + fallback) =

__global__ __launch_bounds__(256) void build_kernel(
    const int* __restrict__ ei, const float* __restrict__ ew,
    const int* __restrict__ mask,
    const float* __restrict__ W1, const float* __restrict__ W2,
    const float* __restrict__ W3,
    int* __restrict__ cursor, unsigned int* __restrict__ bkt,
    _Float16* __restrict__ Wt1, _Float16* __restrict__ Wt2,
    _Float16* __restrict__ Wt3,
    int* __restrict__ vlist, int* __restrict__ validN)
{
    __shared__ int sums[256];
    const int blk = blockIdx.x;
    const int t   = threadIdx.x;

    if (blk < 4096) {
        const int idx = blk * 256 + t;
        const int b = idx >> 16;
        const int e = idx & (NEDGE - 1);
        const int* eib = ei + (size_t)b * 2 * NEDGE;
        const int u = eib[e];
        const int v = eib[NEDGE + e];
        const int mrow = b * NNODE;
        if (mask[mrow + u] != 0 && mask[mrow + v] != 0) {
            const _Float16 w = (_Float16)ew[(size_t)b * NEDGE + e];
            const unsigned short wb = __builtin_bit_cast(unsigned short, w);
            const int pos = atomicAdd(&cursor[mrow + v], 1);
            if (pos < DCAP)
                bkt[(size_t)(mrow + v) * DCAP + pos] = ((unsigned)wb << 16) | (unsigned)u;
        }
    } else if (blk < 4608) {
        const int i = (blk - 4096) * 256 + t;
        if (i < 32768) {
            int k = i >> 8, n = i & 255;
            Wt1[n * 128 + k] = (_Float16)W1[i];
        } else if (i < 98304) {
            int j = i - 32768;
            int k = j >> 8, n = j & 255;
            Wt2[n * 256 + k] = (_Float16)W2[j];
        } else {
            int j = i - 98304;
            int k = j >> 7, n = j & 127;
            Wt3[n * 256 + k] = (_Float16)W3[j];
        }
    } else {
        const int b = blk - 4608;
        const int* mb = mask + b * NNODE;
        for (int i = t; i < CAP; i += 256) vlist[b * CAP + i] = 0;

        int loc[16]; int s = 0;
        #pragma unroll
        for (int i = 0; i < 16; ++i) { loc[i] = (mb[t * 16 + i] != 0); s += loc[i]; }
        sums[t] = s;
        __syncthreads();
        for (int off = 1; off < 256; off <<= 1) {
            int v = (t >= off) ? sums[t - off] : 0;
            __syncthreads();
            sums[t] += v;
            __syncthreads();
        }
        int run = (t == 0) ? 0 : sums[t - 1];
        #pragma unroll
        for (int i = 0; i < 16; ++i) {
            const int n = t * 16 + i;
            if (loc[i]) {
                if (run < CAP) vlist[b * CAP + run] = n;
                ++run;
            }
        }
        if (t == 255) validN[b] = run;
    }
}

__global__ __launch_bounds__(256) void gather_x(
    const int* __restrict__ cursor, const unsigned int* __restrict__ bkt,
    const float* __restrict__ X, const int* __restrict__ vlist,
    const int* __restrict__ validN, _Float16* __restrict__ AggX)
{
    constexpr int NU = CAP / 4;
    const int lane = threadIdx.x & 63;
    const int wave = threadIdx.x >> 6;
    const int xcd  = blockIdx.x & 7;
    const int jj   = blockIdx.x >> 3;
    const int batch = 2 * xcd + (jj >= NU);
    const int unit  = (jj >= NU) ? jj - NU : jj;

    const int j = unit * 4 + wave;
    if (j >= validN[batch]) return;
    const int mrow = batch * NNODE;
    const int v = vlist[batch * CAP + j];
    int deg = cursor[mrow + v];
    deg = deg > DCAP ? DCAP : deg;
    const unsigned* bk = bkt + (size_t)(mrow + v) * DCAP;
    const float* Xb = X + (size_t)mrow * 128 + lane * 2;

    float a0 = 0.0f, a1 = 0.0f;
    for (int i = 0; i < deg; i += 8) {
        const int cnt = deg - i;
        unsigned pk[8];
        #pragma unroll
        for (int t = 0; t < 8; ++t) pk[t] = bk[i + t];
        float wj[8]; float2 xv[8];
        #pragma unroll
        for (int t = 0; t < 8; ++t) {
            const bool ok = (t < cnt);
            const unsigned u = pk[t] & 0xFFFu;
            wj[t] = ok ? (float)__builtin_bit_cast(_Float16, (unsigned short)(pk[t] >> 16)) : 0.0f;
            xv[t] = *(const float2*)(Xb + (size_t)u * 128);
        }
        #pragma unroll
        for (int t = 0; t < 8; ++t) { a0 += wj[t] * xv[t].x; a1 += wj[t] * xv[t].y; }
    }
    half2v o = {(_Float16)a0, (_Float16)a1};
    *(half2v*)&AggX[(size_t)(batch * CAP + j) * 128 + lane * 2] = o;
}

__global__ __launch_bounds__(256) void gather_agg(
    const int* __restrict__ cursor, const unsigned int* __restrict__ bkt,
    const _Float16* __restrict__ Ac, const int* __restrict__ vlist,
    const int* __restrict__ validN, _Float16* __restrict__ AggA)
{
    constexpr int NU = CAP / 4;
    const int lane = threadIdx.x & 63;
    const int wave = threadIdx.x >> 6;
    const int xcd  = blockIdx.x & 7;
    const int jj   = blockIdx.x >> 3;
    const int batch = 2 * xcd + (jj >= NU);
    const int unit  = (jj >= NU) ? jj - NU : jj;

    const int j = unit * 4 + wave;
    if (j >= validN[batch]) return;
    const int mrow = batch * NNODE;
    const int v = vlist[batch * CAP + j];
    int deg = cursor[mrow + v];
    deg = deg > DCAP ? DCAP : deg;
    const unsigned* bk = bkt + (size_t)(mrow + v) * DCAP;
    const _Float16* Ab = Ac + (size_t)mrow * 256 + lane * 4;

    float a0 = 0.0f, a1 = 0.0f, a2 = 0.0f, a3 = 0.0f;
    for (int i = 0; i < deg; i += 8) {
        const int cnt = deg - i;
        unsigned pk[8];
        #pragma unroll
        for (int t = 0; t < 8; ++t) pk[t] = bk[i + t];
        float wj[8]; half4v hv[8];
        #pragma unroll
        for (int t = 0; t < 8; ++t) {
            const bool ok = (t < cnt);
            const unsigned u = pk[t] & 0xFFFu;
            wj[t] = ok ? (float)__builtin_bit_cast(_Float16, (unsigned short)(pk[t] >> 16)) : 0.0f;
            hv[t] = *(const half4v*)(Ab + (size_t)u * 256);
        }
        #pragma unroll
        for (int t = 0; t < 8; ++t) {
            a0 += wj[t] * (float)hv[t][0];
            a1 += wj[t] * (float)hv[t][1];
            a2 += wj[t] * (float)hv[t][2];
            a3 += wj[t] * (float)hv[t][3];
        }
    }
    half4v o = {(_Float16)a0, (_Float16)a1, (_Float16)a2, (_Float16)a3};
    *(half4v*)&AggA[(size_t)(batch * CAP + j) * 256 + lane * 4] = o;
}

__global__ __launch_bounds__(256, 3) void gemm1_kernel(
    const _Float16* __restrict__ Xc, const int* __restrict__ vlist,
    const int* __restrict__ validN, const _Float16* __restrict__ Wt,
    const float* __restrict__ bias, _Float16* __restrict__ Ac)
{
    constexpr int K = 128, NW = 64, NI = 4, RST = 72;
    constexpr int NPAN = 4;
    constexpr int NCH  = CAP / 64;
    constexpr int ASZ  = (NPAN * 2048) > (4 * 16 * RST) ? (NPAN * 2048) : (4 * 16 * RST);
    __shared__ _Float16 A16[ASZ];
    __shared__ int s_v[64];

    const int tid  = threadIdx.x;
    const int lane = tid & 63;
    const int wave = tid >> 6;
    const int quad = lane >> 4;
    const int l15  = lane & 15;

    const int xcd  = blockIdx.x & 7;
    const int j    = blockIdx.x >> 3;
    const int batch = 2 * xcd + (j >= NCH);
    const int tile  = (j >= NCH) ? j - NCH : j;
    const int vN   = validN[batch];
    if (tile * 64 >= vN) return;
    const int mrow = batch * NNODE;
    const size_t bm = (size_t)batch * CAP + (size_t)tile * 64;

    if (tid < 64) {
        const int slot = tile * 64 + tid;
        s_v[tid] = (slot < vN) ? vlist[batch * CAP + slot] : 0;
    }
    const int srow = tid >> 2;
    const int sch  = (tid & 3) * 8;
    #pragma unroll
    for (int pp = 0; pp < NPAN; ++pp)
        __builtin_amdgcn_global_load_lds(
            GP(Xc + (bm + srow) * K + pp * 32 + sch),
            LP(A16 + pp * 2048 + tid * 8), 16, 0, 0);
    __syncthreads();

    f32x4 acc[4][NI];
    #pragma unroll
    for (int mi = 0; mi < 4; ++mi)
        #pragma unroll
        for (int ni = 0; ni < NI; ++ni) acc[mi][ni] = (f32x4)0.0f;

    const _Float16* ap = A16 + l15 * 32 + quad * 8;
    const _Float16* wp = Wt + (size_t)(wave * NW + l15) * K + quad * 8;

    #pragma unroll
    for (int pp = 0; pp < NPAN; ++pp) {
        half8 af[4], bf[NI];
        #pragma unroll
        for (int mi = 0; mi < 4; ++mi)
            af[mi] = *(const half8*)(ap + pp * 2048 + mi * 16 * 32);
        #pragma unroll
        for (int ni = 0; ni < NI; ++ni)
            bf[ni] = *(const half8*)(wp + (size_t)ni * 16 * K + pp * 32);
        #pragma unroll
        for (int mi = 0; mi < 4; ++mi)
            #pragma unroll
            for (int ni = 0; ni < NI; ++ni)
                acc[mi][ni] = __builtin_amdgcn_mfma_f32_16x16x32_f16(
                    bf[ni], af[mi], acc[mi][ni], 0, 0, 0);
    }
    __syncthreads();

    _Float16* stg = A16 + wave * 16 * RST;
    const int rr = lane >> 2;
    const int c0 = lane & 3;
    #pragma unroll
    for (int mi = 0; mi < 4; ++mi) {
        #pragma unroll
        for (int ni = 0; ni < NI; ++ni) {
            f32x4 v = acc[mi][ni];
            const f32x4 bv = *(const f32x4*)&bias[wave * NW + ni * 16 + quad * 4];
            half4v o;
            #pragma unroll
            for (int r = 0; r < 4; ++r) o[r] = (_Float16)fmaxf(v[r] + bv[r], 0.0f);
            *(half4v*)&stg[l15 * RST + ni * 16 + quad * 4] = o;
        }
        const int slot = tile * 64 + mi * 16 + rr;
        if (slot < vN) {
            const int vs = s_v[mi * 16 + rr];
            _Float16* hp2 = &Ac[((size_t)mrow + vs) * 256 + wave * NW];
            #pragma unroll
            for (int c = 0; c < NI / 2; ++c) {
                const int ch = (c0 + 4 * c) * 8;
                half8 v = *(const half8*)&stg[rr * RST + ch];
                *(half8*)(hp2 + ch) = v;
            }
        }
    }
}

__global__ __launch_bounds__(256, 3) void gemm23_kernel(
    const _Float16* __restrict__ Xc, const int* __restrict__ vlist,
    const int* __restrict__ validN, const _Float16* __restrict__ Wt2,
    const _Float16* __restrict__ Wt3, const float* __restrict__ b2,
    _Float16* __restrict__ H3)
{
    constexpr int K    = 256;
    constexpr int NPAN = 8;
    constexpr int NCH  = CAP / 64;
    __shared__ _Float16 A16[NPAN * 2048];
    __shared__ int s_v[64];

    const int tid  = threadIdx.x;
    const int lane = tid & 63;
    const int wave = tid >> 6;
    const int quad = lane >> 4;
    const int l15  = lane & 15;

    const int xcd  = blockIdx.x & 7;
    const int j    = blockIdx.x >> 3;
    const int batch = 2 * xcd + (j >= NCH);
    const int tile  = (j >= NCH) ? j - NCH : j;
    const int vN   = validN[batch];
    if (tile * 64 >= vN) return;
    const int mrow = batch * NNODE;
    const size_t bm = (size_t)batch * CAP + (size_t)tile * 64;

    if (tid < 64) {
        const int slot = tile * 64 + tid;
        s_v[tid] = (slot < vN) ? vlist[batch * CAP + slot] : 0;
    }
    const int srow = tid >> 2;
    const int sch  = (tid & 3) * 8;
    #pragma unroll
    for (int pp = 0; pp < NPAN; ++pp)
        __builtin_amdgcn_global_load_lds(
            GP(Xc + (bm + srow) * K + pp * 32 + sch),
            LP(A16 + pp * 2048 + tid * 8), 16, 0, 0);
    __syncthreads();

    f32x4 acc[4][4];
    #pragma unroll
    for (int mi = 0; mi < 4; ++mi)
        #pragma unroll
        for (int ni = 0; ni < 4; ++ni) acc[mi][ni] = (f32x4)0.0f;

    const _Float16* ap = A16 + l15 * 32 + quad * 8;
    const _Float16* wp = Wt2 + (size_t)(wave * 64 + l15) * K + quad * 8;

    #pragma unroll
    for (int pp = 0; pp < NPAN; ++pp) {
        half8 af[4], bf[4];
        #pragma unroll
        for (int mi = 0; mi < 4; ++mi)
            af[mi] = *(const half8*)(ap + pp * 2048 + mi * 16 * 32);
        #pragma unroll
        for (int ni = 0; ni < 4; ++ni)
            bf[ni] = *(const half8*)(wp + (size_t)ni * 16 * K + pp * 32);
        #pragma unroll
        for (int mi = 0; mi < 4; ++mi)
            #pragma unroll
            for (int ni = 0; ni < 4; ++ni)
                acc[mi][ni] = __builtin_amdgcn_mfma_f32_16x16x32_f16(
                    bf[ni], af[mi], acc[mi][ni], 0, 0, 0);
    }
    __syncthreads();

    #pragma unroll
    for (int mi = 0; mi < 4; ++mi) {
        const int row = mi * 16 + l15;
        #pragma unroll
        for (int ni = 0; ni < 4; ++ni) {
            const int col = wave * 64 + ni * 16 + quad * 4;
            const f32x4 bv = *(const f32x4*)&b2[col];
            f32x4 v = acc[mi][ni];
            half4v o;
            #pragma unroll
            for (int r = 0; r < 4; ++r) o[r] = (_Float16)fmaxf(v[r] + bv[r], 0.0f);
            *(half4v*)&A16[(col >> 5) * 2048 + row * 32 + (col & 31)] = o;
        }
    }
    __syncthreads();

    f32x4 acc2[4][2];
    #pragma unroll
    for (int mi = 0; mi < 4; ++mi)
        #pragma unroll
        for (int ni = 0; ni < 2; ++ni) acc2[mi][ni] = (f32x4)0.0f;

    const _Float16* wp3 = Wt3 + (size_t)(wave * 32 + l15) * K + quad * 8;
    #pragma unroll
    for (int pp = 0; pp < NPAN; ++pp) {
        half8 af[4], bf[2];
        #pragma unroll
        for (int mi = 0; mi < 4; ++mi)
            af[mi] = *(const half8*)(ap + pp * 2048 + mi * 16 * 32);
        #pragma unroll
        for (int ni = 0; ni < 2; ++ni)
            bf[ni] = *(const half8*)(wp3 + (size_t)ni * 16 * K + pp * 32);
        #pragma unroll
        for (int mi = 0; mi < 4; ++mi)
            #pragma unroll
            for (int ni = 0; ni < 2; ++ni)
                acc2[mi][ni] = __builtin_amdgcn_mfma_f32_16x16x32_f16(
                    bf[ni], af[mi], acc2[mi][ni], 0, 0, 0);
    }
    __syncthreads();

    constexpr int RST = 40;
    _Float16* stg = A16 + wave * 16 * RST;
    const int rr = lane >> 2;
    const int c0 = lane & 3;
    #pragma unroll
    for (int mi = 0; mi < 4; ++mi) {
        #pragma unroll
        for (int ni = 0; ni < 2; ++ni) {
            f32x4 v = acc2[mi][ni];
            half4v o;
            #pragma unroll
            for (int r = 0; r < 4; ++r) o[r] = (_Float16)v[r];
            *(half4v*)&stg[l15 * RST + ni * 16 + quad * 4] = o;
        }
        const int slot = tile * 64 + mi * 16 + rr;
        if (slot < vN) {
            const int vs = s_v[mi * 16 + rr];
            _Float16* hp2 = &H3[((size_t)mrow + vs) * 128 + wave * 32];
            const int ch = c0 * 8;
            half8 v = *(const half8*)&stg[rr * RST + ch];
            *(half8*)(hp2 + ch) = v;
        }
    }
}

__global__ __launch_bounds__(256) void gather_final(
    const int* __restrict__ cursor, const unsigned int* __restrict__ bkt,
    const _Float16* __restrict__ H3, const int* __restrict__ mask,
    const float* __restrict__ bias, float* __restrict__ OUT)
{
    constexpr int NU = NNODE / 4;
    const int lane = threadIdx.x & 63;
    const int wave = threadIdx.x >> 6;

    const int xcd  = blockIdx.x & 7;
    const int jj   = blockIdx.x >> 3;
    const int batch = 2 * xcd + (jj >= NU);
    const int unit  = (jj >= NU) ? jj - NU : jj;

    const int n = unit * 4 + wave;
    const int mrow = batch * NNODE + n;

    float acc[2] = {};
    if (mask[mrow] != 0) {
        int deg = cursor[mrow];
        deg = deg > DCAP ? DCAP : deg;
        const unsigned* bk = bkt + (size_t)mrow * DCAP;
        const _Float16* Hb = H3 + (size_t)batch * NNODE * 128 + lane * 2;

        for (int i = 0; i < deg; i += 8) {
            const int cnt = deg - i;
            unsigned pk[8];
            #pragma unroll
            for (int t = 0; t < 8; ++t) pk[t] = bk[i + t];
            float wj[8]; const _Float16* hp[8];
            #pragma unroll
            for (int t = 0; t < 8; ++t) {
                const bool ok = (t < cnt);
                const unsigned u = pk[t] & 0xFFFu;
                wj[t] = ok ? (float)__builtin_bit_cast(_Float16, (unsigned short)(pk[t] >> 16)) : 0.0f;
                hp[t] = Hb + (size_t)u * 128;
            }
            half2v hv[8];
            #pragma unroll
            for (int t = 0; t < 8; ++t) hv[t] = *(const half2v*)hp[t];
            #pragma unroll
            for (int t = 0; t < 8; ++t)
                #pragma unroll
                for (int c = 0; c < 2; ++c) acc[c] += wj[t] * (float)hv[t][c];
        }
        #pragma unroll
        for (int c = 0; c < 2; ++c)
            acc[c] = fmaxf(acc[c] + bias[lane * 2 + c], 0.0f);
    }
    f32x2 o = {acc[0], acc[1]};
    *(f32x2*)&OUT[(size_t)mrow * 128 + lane * 2] = o;
}

extern "C" void kernel_launch(void* const* d_in, const int* in_sizes, int n_in,
                              void* d_out, int out_size, void* d_ws, size_t ws_size,
                              hipStream_t stream) {
    const float* x    = (const float*)d_in[0];
    const int*   ei   = (const int*)  d_in[1];
    const float* ew   = (const float*)d_in[2];
    const int*   mask = (const int*)  d_in[3];
    const float* W1   = (const float*)d_in[4];
    const float* b1   = (const float*)d_in[5];
    const float* W2   = (const float*)d_in[6];
    const float* b2   = (const float*)d_in[7];
    const float* W3   = (const float*)d_in[8];
    const float* b3   = (const float*)d_in[9];
    float* out = (float*)d_out;

    // Workspace layout (~95 MB):
    char* ws = (char*)d_ws;
    _Float16* Ac   = (_Float16*)(ws);                      // 32 MB [ROWS,256] full
    _Float16* H3   = (_Float16*)(ws + (32u << 20));        // 16 MB [ROWS,128] full
    unsigned int* bkt = (unsigned int*)(ws + (48u << 20)); // 16 MB [ROWS,DCAP]
    _Float16* AggX = (_Float16*)(ws + (64u << 20));        // 10 MB [PM,128] compact
    _Float16* AggA = (_Float16*)(ws + (74u << 20));        // 20 MB [PM,256] compact
    _Float16* Wt1  = (_Float16*)(ws + (94u << 20));        // 64 KB
    _Float16* Wt2  = Wt1 + 128 * 256;                      // 128 KB
    _Float16* Wt3  = Wt2 + 256 * 256;                      // 64 KB
    int* cursor    = (int*)(Wt3 + 256 * 128);              // 256 KB (degrees)
    int* vlist     = cursor + ROWS;                        // 152 KB
    int* validN    = vlist + PM;

    const dim3 blk(256);
    const int gemmBlocks = PM / 64;      // 608
    const int aggBlocks  = PM / 4;       // 9728
    const int finBlocks  = ROWS / 4;     // 16384

    // ---- dispatch 1: cooperative {zero, build, gather_x} ----
    void* args[] = {
        (void*)&ei, (void*)&ew, (void*)&mask, (void*)&x,
        (void*)&W1, (void*)&W2, (void*)&W3,
        (void*)&cursor, (void*)&bkt, (void*)&Wt1, (void*)&Wt2, (void*)&Wt3,
        (void*)&vlist, (void*)&validN, (void*)&AggX };
    hipError_t err = hipLaunchCooperativeKernel(
        reinterpret_cast<void*>(coop_build), dim3(GRID_B), blk, args, 0, stream);
    if (err != hipSuccess) {
        // fallback: round-9 verified 3-dispatch front end
        hipMemsetAsync(cursor, 0, (size_t)ROWS * sizeof(int), stream);
        build_kernel<<<4624, blk, 0, stream>>>(ei, ew, mask, W1, W2, W3,
                                               cursor, bkt, Wt1, Wt2, Wt3,
                                               vlist, validN);
        gather_x<<<aggBlocks, blk, 0, stream>>>(cursor, bkt, x, vlist, validN, AggX);
    }

    // ---- dispatches 2-5: round-9 verified back end ----
    gemm1_kernel<<<gemmBlocks, blk, 0, stream>>>(AggX, vlist, validN, Wt1, b1, Ac);
    gather_agg<<<aggBlocks, blk, 0, stream>>>(cursor, bkt, Ac, vlist, validN, AggA);
    gemm23_kernel<<<gemmBlocks, blk, 0, stream>>>(AggA, vlist, validN, Wt2, Wt3, b2, H3);
    gather_final<<<finBlocks, blk, 0, stream>>>(cursor, bkt, H3, mask, b3, out);
}

// Round 12
// 208.355 us; speedup vs baseline: 5.3951x; 2.4994x over previous
//
#include <hip/hip_runtime.h>

static constexpr int BATCH = 16;
static constexpr int NNODE = 4096;
static constexpr int NEDGE = 65536;            // 1 << 16
static constexpr int ROWS  = BATCH * NNODE;    // 65536
static constexpr int CAP   = 2432;             // compacted slots/batch (38*64)
static constexpr int PM    = BATCH * CAP;
static constexpr int DCAP  = 64;               // per-node edge-bucket capacity

typedef _Float16 half8  __attribute__((ext_vector_type(8)));
typedef _Float16 half4v __attribute__((ext_vector_type(4)));
typedef _Float16 half2v __attribute__((ext_vector_type(2)));
typedef float    f32x4  __attribute__((ext_vector_type(4)));
typedef float    f32x2  __attribute__((ext_vector_type(2)));

#define GP(p) (const __attribute__((address_space(1))) void*)(p)
#define LP(p) (__attribute__((address_space(3))) void*)(p)

// ---------------- build: bucket fill + W cast + compaction (one dispatch) ---
// Edge pass: 2 edges/thread, int2/float2 vectorized (round-12: halves the
// largest grid; 2048+512+16 = 2576 blocks).
__global__ __launch_bounds__(256) void build_kernel(
    const int* __restrict__ ei, const float* __restrict__ ew,
    const int* __restrict__ mask,
    const float* __restrict__ W1, const float* __restrict__ W2,
    const float* __restrict__ W3,
    int* __restrict__ cursor, unsigned int* __restrict__ bkt,
    _Float16* __restrict__ Wt1, _Float16* __restrict__ Wt2,
    _Float16* __restrict__ Wt3,
    int* __restrict__ vlist, int* __restrict__ validN)
{
    __shared__ int sums[256];
    const int blk = blockIdx.x;
    const int t   = threadIdx.x;

    if (blk < 2048) {
        // bkt entry = (fp16bits(w) << 16) | raw_u  (u < 4096 fits 12 bits)
        const int idx = blk * 256 + t;             // [0, BATCH*NEDGE/2)
        const int e0  = idx * 2;                   // even; e0,e0+1 same batch
        const int b   = e0 >> 16;
        const int e   = e0 & (NEDGE - 1);
        const int* eib = ei + (size_t)b * 2 * NEDGE;
        const int2 u2 = *(const int2*)&eib[e];
        const int2 v2 = *(const int2*)&eib[NEDGE + e];
        const float2 w2 = *(const float2*)&ew[(size_t)b * NEDGE + e];
        const int mrow = b * NNODE;
        if (mask[mrow + u2.x] != 0 && mask[mrow + v2.x] != 0) {
            const unsigned short wb = __builtin_bit_cast(unsigned short, (_Float16)w2.x);
            const int pos = atomicAdd(&cursor[mrow + v2.x], 1);
            if (pos < DCAP)
                bkt[(size_t)(mrow + v2.x) * DCAP + pos] = ((unsigned)wb << 16) | (unsigned)u2.x;
        }
        if (mask[mrow + u2.y] != 0 && mask[mrow + v2.y] != 0) {
            const unsigned short wb = __builtin_bit_cast(unsigned short, (_Float16)w2.y);
            const int pos = atomicAdd(&cursor[mrow + v2.y], 1);
            if (pos < DCAP)
                bkt[(size_t)(mrow + v2.y) * DCAP + pos] = ((unsigned)wb << 16) | (unsigned)u2.y;
        }
    } else if (blk < 2560) {
        const int i = (blk - 2048) * 256 + t;      // [0, 131072)
        if (i < 32768) {
            int k = i >> 8, n = i & 255;
            Wt1[n * 128 + k] = (_Float16)W1[i];
        } else if (i < 98304) {
            int j = i - 32768;
            int k = j >> 8, n = j & 255;
            Wt2[n * 256 + k] = (_Float16)W2[j];
        } else {
            int j = i - 98304;
            int k = j >> 7, n = j & 127;
            Wt3[n * 256 + k] = (_Float16)W3[j];
        }
    } else {
        // per-batch node compaction
        const int b = blk - 2560;
        const int* mb = mask + b * NNODE;
        for (int i = t; i < CAP; i += 256) vlist[b * CAP + i] = 0;

        int loc[16]; int s = 0;
        #pragma unroll
        for (int i = 0; i < 16; ++i) { loc[i] = (mb[t * 16 + i] != 0); s += loc[i]; }
        sums[t] = s;
        __syncthreads();
        for (int off = 1; off < 256; off <<= 1) {
            int v = (t >= off) ? sums[t - off] : 0;
            __syncthreads();
            sums[t] += v;
            __syncthreads();
        }
        int run = (t == 0) ? 0 : sums[t - 1];
        #pragma unroll
        for (int i = 0; i < 16; ++i) {
            const int n = t * 16 + i;
            if (loc[i]) {
                if (run < CAP) vlist[b * CAP + run] = n;
                ++run;
            }
        }
        if (t == 255) validN[b] = run;
    }
}

// ---------------- standalone gathers: 1 slot/wave, TLP hides latency --------
// 38912 waves (152/CU) — per-wave load serialization is irrelevant at this
// oversubscription (rounds 4/7/8: in-kernel gather ILP unattainable — the
// allocator serializes or spills; rounds 10/11: cooperative phase fusion
// loses ~170 us per grid.sync).

__global__ __launch_bounds__(256) void gather_x(
    const int* __restrict__ cursor, const unsigned int* __restrict__ bkt,
    const float* __restrict__ X,       // [ROWS, 128] f32 (input)
    const int* __restrict__ vlist, const int* __restrict__ validN,
    _Float16* __restrict__ AggX)       // [PM, 128] compact
{
    constexpr int NU = CAP / 4;        // 608
    const int lane = threadIdx.x & 63;
    const int wave = threadIdx.x >> 6;
    const int xcd  = blockIdx.x & 7;
    const int jj   = blockIdx.x >> 3;
    const int batch = 2 * xcd + (jj >= NU);
    const int unit  = (jj >= NU) ? jj - NU : jj;

    const int j = unit * 4 + wave;
    if (j >= validN[batch]) return;
    const int mrow = batch * NNODE;
    const int v = vlist[batch * CAP + j];
    int deg = cursor[mrow + v];
    deg = deg > DCAP ? DCAP : deg;
    const unsigned* bk = bkt + (size_t)(mrow + v) * DCAP;
    const float* Xb = X + (size_t)mrow * 128 + lane * 2;

    float a0 = 0.0f, a1 = 0.0f;
    for (int i = 0; i < deg; i += 8) {
        const int cnt = deg - i;
        unsigned pk[8];
        #pragma unroll
        for (int t = 0; t < 8; ++t) pk[t] = bk[i + t];   // slack overread in-ws
        float wj[8]; float2 xv[8];
        #pragma unroll
        for (int t = 0; t < 8; ++t) {
            const bool ok = (t < cnt);
            const unsigned u = pk[t] & 0xFFFu;           // < 4096: in-batch
            wj[t] = ok ? (float)__builtin_bit_cast(_Float16, (unsigned short)(pk[t] >> 16)) : 0.0f;
            xv[t] = *(const float2*)(Xb + (size_t)u * 128);
        }
        #pragma unroll
        for (int t = 0; t < 8; ++t) { a0 += wj[t] * xv[t].x; a1 += wj[t] * xv[t].y; }
    }
    half2v o = {(_Float16)a0, (_Float16)a1};
    *(half2v*)&AggX[(size_t)(batch * CAP + j) * 128 + lane * 2] = o;
}

__global__ __launch_bounds__(256) void gather_agg(
    const int* __restrict__ cursor, const unsigned int* __restrict__ bkt,
    const _Float16* __restrict__ Ac,   // [ROWS, 256] full layout
    const int* __restrict__ vlist, const int* __restrict__ validN,
    _Float16* __restrict__ AggA)       // [PM, 256] compact
{
    constexpr int NU = CAP / 4;
    const int lane = threadIdx.x & 63;
    const int wave = threadIdx.x >> 6;
    const int xcd  = blockIdx.x & 7;
    const int jj   = blockIdx.x >> 3;
    const int batch = 2 * xcd + (jj >= NU);
    const int unit  = (jj >= NU) ? jj - NU : jj;

    const int j = unit * 4 + wave;
    if (j >= validN[batch]) return;
    const int mrow = batch * NNODE;
    const int v = vlist[batch * CAP + j];
    int deg = cursor[mrow + v];
    deg = deg > DCAP ? DCAP : deg;
    const unsigned* bk = bkt + (size_t)(mrow + v) * DCAP;
    const _Float16* Ab = Ac + (size_t)mrow * 256 + lane * 4;

    float a0 = 0.0f, a1 = 0.0f, a2 = 0.0f, a3 = 0.0f;
    for (int i = 0; i < deg; i += 8) {
        const int cnt = deg - i;
        unsigned pk[8];
        #pragma unroll
        for (int t = 0; t < 8; ++t) pk[t] = bk[i + t];
        float wj[8]; half4v hv[8];
        #pragma unroll
        for (int t = 0; t < 8; ++t) {
            const bool ok = (t < cnt);
            const unsigned u = pk[t] & 0xFFFu;           // valid u: Ac row written
            wj[t] = ok ? (float)__builtin_bit_cast(_Float16, (unsigned short)(pk[t] >> 16)) : 0.0f;
            hv[t] = *(const half4v*)(Ab + (size_t)u * 256);
        }
        #pragma unroll
        for (int t = 0; t < 8; ++t) {
            a0 += wj[t] * (float)hv[t][0];
            a1 += wj[t] * (float)hv[t][1];
            a2 += wj[t] * (float)hv[t][2];
            a3 += wj[t] * (float)hv[t][3];
        }
    }
    half4v o = {(_Float16)a0, (_Float16)a1, (_Float16)a2, (_Float16)a3};
    *(half4v*)&AggA[(size_t)(batch * CAP + j) * 256 + lane * 4] = o;
}

// ---------------- GEMM layer 1: AggX @ W1 -> relu+b1 -> scatter Ac ---------
__global__ __launch_bounds__(256, 3) void gemm1_kernel(
    const _Float16* __restrict__ Xc,   // AggX [PM, 128] compact
    const int* __restrict__ vlist, const int* __restrict__ validN,
    const _Float16* __restrict__ Wt,   // [256, 128]
    const float* __restrict__ bias,    // b1
    _Float16* __restrict__ Ac)         // [ROWS, 256] full layout
{
    constexpr int K = 128, NW = 64, NI = 4, RST = 72;
    constexpr int NPAN = 4;
    constexpr int NCH  = CAP / 64;     // 38
    constexpr int ASZ  = (NPAN * 2048) > (4 * 16 * RST) ? (NPAN * 2048) : (4 * 16 * RST);
    __shared__ _Float16 A16[ASZ];      // 16 KB, reused for store restage
    __shared__ int s_v[64];

    const int tid  = threadIdx.x;
    const int lane = tid & 63;
    const int wave = tid >> 6;
    const int quad = lane >> 4;
    const int l15  = lane & 15;

    const int xcd  = blockIdx.x & 7;
    const int j    = blockIdx.x >> 3;          // [0, 2*NCH)
    const int batch = 2 * xcd + (j >= NCH);
    const int tile  = (j >= NCH) ? j - NCH : j;
    const int vN   = validN[batch];
    if (tile * 64 >= vN) return;
    const int mrow = batch * NNODE;
    const size_t bm = (size_t)batch * CAP + (size_t)tile * 64;

    if (tid < 64) {
        const int slot = tile * 64 + tid;
        s_v[tid] = (slot < vN) ? vlist[batch * CAP + slot] : 0;
    }
    const int srow = tid >> 2;                 // 0..63
    const int sch  = (tid & 3) * 8;
    #pragma unroll
    for (int pp = 0; pp < NPAN; ++pp)
        __builtin_amdgcn_global_load_lds(
            GP(Xc + (bm + srow) * K + pp * 32 + sch),
            LP(A16 + pp * 2048 + tid * 8), 16, 0, 0);
    __syncthreads();

    f32x4 acc[4][NI];
    #pragma unroll
    for (int mi = 0; mi < 4; ++mi)
        #pragma unroll
        for (int ni = 0; ni < NI; ++ni) acc[mi][ni] = (f32x4)0.0f;

    const _Float16* ap = A16 + l15 * 32 + quad * 8;
    const _Float16* wp = Wt + (size_t)(wave * NW + l15) * K + quad * 8;

    #pragma unroll
    for (int pp = 0; pp < NPAN; ++pp) {
        half8 af[4], bf[NI];
        #pragma unroll
        for (int mi = 0; mi < 4; ++mi)
            af[mi] = *(const half8*)(ap + pp * 2048 + mi * 16 * 32);
        #pragma unroll
        for (int ni = 0; ni < NI; ++ni)
            bf[ni] = *(const half8*)(wp + (size_t)ni * 16 * K + pp * 32);
        #pragma unroll
        for (int mi = 0; mi < 4; ++mi)
            #pragma unroll
            for (int ni = 0; ni < NI; ++ni)
                acc[mi][ni] = __builtin_amdgcn_mfma_f32_16x16x32_f16(
                    bf[ni], af[mi], acc[mi][ni], 0, 0, 0);   // swapped
    }
    __syncthreads();   // A16 free for store restage

    _Float16* stg = A16 + wave * 16 * RST;
    const int rr = lane >> 2;
    const int c0 = lane & 3;
    #pragma unroll
    for (int mi = 0; mi < 4; ++mi) {
        #pragma unroll
        for (int ni = 0; ni < NI; ++ni) {
            f32x4 v = acc[mi][ni];
            const f32x4 bv = *(const f32x4*)&bias[wave * NW + ni * 16 + quad * 4];
            half4v o;
            #pragma unroll
            for (int r = 0; r < 4; ++r) o[r] = (_Float16)fmaxf(v[r] + bv[r], 0.0f);
            *(half4v*)&stg[l15 * RST + ni * 16 + quad * 4] = o;
        }
        const int slot = tile * 64 + mi * 16 + rr;
        if (slot < vN) {
            const int vs = s_v[mi * 16 + rr];
            _Float16* hp2 = &Ac[((size_t)mrow + vs) * 256 + wave * NW];
            #pragma unroll
            for (int c = 0; c < NI / 2; ++c) {
                const int ch = (c0 + 4 * c) * 8;
                half8 v = *(const half8*)&stg[rr * RST + ch];
                *(half8*)(hp2 + ch) = v;
            }
        }
    }
}

// ---------------- GEMM layers 2+3: AggA @ W2 -> relu -> @ W3 -> scatter H3 --
__global__ __launch_bounds__(256, 3) void gemm23_kernel(
    const _Float16* __restrict__ Xc,   // AggA [PM, 256] compact
    const int* __restrict__ vlist, const int* __restrict__ validN,
    const _Float16* __restrict__ Wt2,  // [256, 256]
    const _Float16* __restrict__ Wt3,  // [128, 256]
    const float* __restrict__ b2,
    _Float16* __restrict__ H3)         // [ROWS, 128] full layout
{
    constexpr int K    = 256;
    constexpr int NPAN = 8;
    constexpr int NCH  = CAP / 64;     // 38
    __shared__ _Float16 A16[NPAN * 2048];   // 32 KB, reused 3x
    __shared__ int s_v[64];

    const int tid  = threadIdx.x;
    const int lane = tid & 63;
    const int wave = tid >> 6;
    const int quad = lane >> 4;
    const int l15  = lane & 15;

    const int xcd  = blockIdx.x & 7;
    const int j    = blockIdx.x >> 3;
    const int batch = 2 * xcd + (j >= NCH);
    const int tile  = (j >= NCH) ? j - NCH : j;
    const int vN   = validN[batch];
    if (tile * 64 >= vN) return;
    const int mrow = batch * NNODE;
    const size_t bm = (size_t)batch * CAP + (size_t)tile * 64;

    if (tid < 64) {
        const int slot = tile * 64 + tid;
        s_v[tid] = (slot < vN) ? vlist[batch * CAP + slot] : 0;
    }
    const int srow = tid >> 2;
    const int sch  = (tid & 3) * 8;
    #pragma unroll
    for (int pp = 0; pp < NPAN; ++pp)
        __builtin_amdgcn_global_load_lds(
            GP(Xc + (bm + srow) * K + pp * 32 + sch),
            LP(A16 + pp * 2048 + tid * 8), 16, 0, 0);
    __syncthreads();

    // ---- phase 1: layer-2 matmul (64 cols/wave, NI=4) ----
    f32x4 acc[4][4];
    #pragma unroll
    for (int mi = 0; mi < 4; ++mi)
        #pragma unroll
        for (int ni = 0; ni < 4; ++ni) acc[mi][ni] = (f32x4)0.0f;

    const _Float16* ap = A16 + l15 * 32 + quad * 8;
    const _Float16* wp = Wt2 + (size_t)(wave * 64 + l15) * K + quad * 8;

    #pragma unroll
    for (int pp = 0; pp < NPAN; ++pp) {
        half8 af[4], bf[4];
        #pragma unroll
        for (int mi = 0; mi < 4; ++mi)
            af[mi] = *(const half8*)(ap + pp * 2048 + mi * 16 * 32);
        #pragma unroll
        for (int ni = 0; ni < 4; ++ni)
            bf[ni] = *(const half8*)(wp + (size_t)ni * 16 * K + pp * 32);
        #pragma unroll
        for (int mi = 0; mi < 4; ++mi)
            #pragma unroll
            for (int ni = 0; ni < 4; ++ni)
                acc[mi][ni] = __builtin_amdgcn_mfma_f32_16x16x32_f16(
                    bf[ni], af[mi], acc[mi][ni], 0, 0, 0);
    }
    __syncthreads();   // all waves done reading AggA panels

    // ---- epilogue 1: relu(acc + b2) -> A16 panel layout [pp][row][32] ----
    #pragma unroll
    for (int mi = 0; mi < 4; ++mi) {
        const int row = mi * 16 + l15;
        #pragma unroll
        for (int ni = 0; ni < 4; ++ni) {
            const int col = wave * 64 + ni * 16 + quad * 4;
            const f32x4 bv = *(const f32x4*)&b2[col];
            f32x4 v = acc[mi][ni];
            half4v o;
            #pragma unroll
            for (int r = 0; r < 4; ++r) o[r] = (_Float16)fmaxf(v[r] + bv[r], 0.0f);
            *(half4v*)&A16[(col >> 5) * 2048 + row * 32 + (col & 31)] = o;
        }
    }
    __syncthreads();

    // ---- phase 2: layer-3 matmul from LDS (32 cols/wave, NI=2) ----
    f32x4 acc2[4][2];
    #pragma unroll
    for (int mi = 0; mi < 4; ++mi)
        #pragma unroll
        for (int ni = 0; ni < 2; ++ni) acc2[mi][ni] = (f32x4)0.0f;

    const _Float16* wp3 = Wt3 + (size_t)(wave * 32 + l15) * K + quad * 8;
    #pragma unroll
    for (int pp = 0; pp < NPAN; ++pp) {
        half8 af[4], bf[2];
        #pragma unroll
        for (int mi = 0; mi < 4; ++mi)
            af[mi] = *(const half8*)(ap + pp * 2048 + mi * 16 * 32);
        #pragma unroll
        for (int ni = 0; ni < 2; ++ni)
            bf[ni] = *(const half8*)(wp3 + (size_t)ni * 16 * K + pp * 32);
        #pragma unroll
        for (int mi = 0; mi < 4; ++mi)
            #pragma unroll
            for (int ni = 0; ni < 2; ++ni)
                acc2[mi][ni] = __builtin_amdgcn_mfma_f32_16x16x32_f16(
                    bf[ni], af[mi], acc2[mi][ni], 0, 0, 0);
    }
    __syncthreads();   // A16 free for store restage

    constexpr int RST = 40;            // 32 + 8 pad
    _Float16* stg = A16 + wave * 16 * RST;
    const int rr = lane >> 2;
    const int c0 = lane & 3;
    #pragma unroll
    for (int mi = 0; mi < 4; ++mi) {
        #pragma unroll
        for (int ni = 0; ni < 2; ++ni) {
            f32x4 v = acc2[mi][ni];
            half4v o;
            #pragma unroll
            for (int r = 0; r < 4; ++r) o[r] = (_Float16)v[r];
            *(half4v*)&stg[l15 * RST + ni * 16 + quad * 4] = o;
        }
        const int slot = tile * 64 + mi * 16 + rr;
        if (slot < vN) {
            const int vs = s_v[mi * 16 + rr];
            _Float16* hp2 = &H3[((size_t)mrow + vs) * 128 + wave * 32];
            const int ch = c0 * 8;
            half8 v = *(const half8*)&stg[rr * RST + ch];
            *(half8*)(hp2 + ch) = v;
        }
    }
}

// ---------------- final gather (1 node/wave, static XCD-affine) -------------
__global__ __launch_bounds__(256) void gather_final(
    const int* __restrict__ cursor, const unsigned int* __restrict__ bkt,
    const _Float16* __restrict__ H3,   // [ROWS, 128]
    const int* __restrict__ mask, const float* __restrict__ bias,
    float* __restrict__ OUT)           // [ROWS, 128]
{
    constexpr int NU = NNODE / 4;      // 1024 units (4 nodes) per batch
    const int lane = threadIdx.x & 63;
    const int wave = threadIdx.x >> 6;

    const int xcd  = blockIdx.x & 7;
    const int jj   = blockIdx.x >> 3;
    const int batch = 2 * xcd + (jj >= NU);
    const int unit  = (jj >= NU) ? jj - NU : jj;

    const int n = unit * 4 + wave;
    const int mrow = batch * NNODE + n;

    float acc[2] = {};
    if (mask[mrow] != 0) {
        int deg = cursor[mrow];
        deg = deg > DCAP ? DCAP : deg;
        const unsigned* bk = bkt + (size_t)mrow * DCAP;
        const _Float16* Hb = H3 + (size_t)batch * NNODE * 128 + lane * 2;

        for (int i = 0; i < deg; i += 8) {
            const int cnt = deg - i;
            unsigned pk[8];
            #pragma unroll
            for (int t = 0; t < 8; ++t) pk[t] = bk[i + t];
            float wj[8]; const _Float16* hp[8];
            #pragma unroll
            for (int t = 0; t < 8; ++t) {
                const bool ok = (t < cnt);
                const unsigned u = pk[t] & 0xFFFu;
                wj[t] = ok ? (float)__builtin_bit_cast(_Float16, (unsigned short)(pk[t] >> 16)) : 0.0f;
                hp[t] = Hb + (size_t)u * 128;
            }
            half2v hv[8];
            #pragma unroll
            for (int t = 0; t < 8; ++t) hv[t] = *(const half2v*)hp[t];
            #pragma unroll
            for (int t = 0; t < 8; ++t)
                #pragma unroll
                for (int c = 0; c < 2; ++c) acc[c] += wj[t] * (float)hv[t][c];
        }
        #pragma unroll
        for (int c = 0; c < 2; ++c)
            acc[c] = fmaxf(acc[c] + bias[lane * 2 + c], 0.0f);
    }
    f32x2 o = {acc[0], acc[1]};
    *(f32x2*)&OUT[(size_t)mrow * 128 + lane * 2] = o;
}

extern "C" void kernel_launch(void* const* d_in, const int* in_sizes, int n_in,
                              void* d_out, int out_size, void* d_ws, size_t ws_size,
                              hipStream_t stream) {
    const float* x    = (const float*)d_in[0];
    const int*   ei   = (const int*)  d_in[1];
    const float* ew   = (const float*)d_in[2];
    const int*   mask = (const int*)  d_in[3];
    const float* W1   = (const float*)d_in[4];
    const float* b1   = (const float*)d_in[5];
    const float* W2   = (const float*)d_in[6];
    const float* b2   = (const float*)d_in[7];
    const float* W3   = (const float*)d_in[8];
    const float* b3   = (const float*)d_in[9];
    float* out = (float*)d_out;

    // Workspace layout (~95 MB):
    char* ws = (char*)d_ws;
    _Float16* Ac   = (_Float16*)(ws);                      // 32 MB [ROWS,256] full
    _Float16* H3   = (_Float16*)(ws + (32u << 20));        // 16 MB [ROWS,128] full
    unsigned int* bkt = (unsigned int*)(ws + (48u << 20)); // 16 MB [ROWS,DCAP]
    _Float16* AggX = (_Float16*)(ws + (64u << 20));        // 10 MB [PM,128] compact
    _Float16* AggA = (_Float16*)(ws + (74u << 20));        // 20 MB [PM,256] compact
    _Float16* Wt1  = (_Float16*)(ws + (94u << 20));        // 64 KB
    _Float16* Wt2  = Wt1 + 128 * 256;                      // 128 KB
    _Float16* Wt3  = Wt2 + 256 * 256;                      // 64 KB
    int* cursor    = (int*)(Wt3 + 256 * 128);              // 256 KB (degrees)
    int* vlist     = cursor + ROWS;                        // 152 KB
    int* validN    = vlist + PM;

    const dim3 blk(256);

    // ---- 1. zero degree cursors ----
    hipMemsetAsync(cursor, 0, (size_t)ROWS * sizeof(int), stream);

    // ---- 2. build: buckets (2 edges/thread) + W casts + compaction ----
    build_kernel<<<2576, blk, 0, stream>>>(ei, ew, mask, W1, W2, W3,
                                           cursor, bkt, Wt1, Wt2, Wt3,
                                           vlist, validN);

    const int gemmBlocks = PM / 64;      // 608
    const int aggBlocks  = PM / 4;       // 9728
    const int finBlocks  = ROWS / 4;     // 16384

    // ---- 3. layer 1: standalone aggregation (agg-first linearity), GEMM ----
    gather_x<<<aggBlocks, blk, 0, stream>>>(cursor, bkt, x, vlist, validN, AggX);
    gemm1_kernel<<<gemmBlocks, blk, 0, stream>>>(AggX, vlist, validN, Wt1, b1, Ac);

    // ---- 4. layers 2+3: standalone aggregation, fused 2-layer GEMM ----
    gather_agg<<<aggBlocks, blk, 0, stream>>>(cursor, bkt, Ac, vlist, validN, AggA);
    gemm23_kernel<<<gemmBlocks, blk, 0, stream>>>(AggA, vlist, validN, Wt2, Wt3, b2, H3);

    // ---- 5. layer-3 aggregation + bias/relu/mask ----
    gather_final<<<finBlocks, blk, 0, stream>>>(cursor, bkt, H3, mask, b3, out);
}

// Round 13
// 206.018 us; speedup vs baseline: 5.4563x; 1.0113x over previous
//
#include <hip/hip_runtime.h>

static constexpr int BATCH = 16;
static constexpr int NNODE = 4096;
static constexpr int NEDGE = 65536;            // 1 << 16
static constexpr int ROWS  = BATCH * NNODE;    // 65536
static constexpr int CAP   = 2432;             // compacted slots/batch (38*64)
static constexpr int PM    = BATCH * CAP;
static constexpr int DCAP  = 64;               // per-node edge-bucket capacity

typedef _Float16 half8  __attribute__((ext_vector_type(8)));
typedef _Float16 half4v __attribute__((ext_vector_type(4)));
typedef _Float16 half2v __attribute__((ext_vector_type(2)));
typedef float    f32x4  __attribute__((ext_vector_type(4)));
typedef float    f32x2  __attribute__((ext_vector_type(2)));

#define GP(p) (const __attribute__((address_space(1))) void*)(p)
#define LP(p) (__attribute__((address_space(3))) void*)(p)

// ---------------- build: bucket fill + W cast + compaction (one dispatch) ---
// Edge pass: 2 edges/thread; per-block 16 KB LDS stage of the batch's mask
// (each block's 512 edges are same-batch) — mask lookups gate the atomics
// and were random ~150-cy L2 hits; now LDS.
__global__ __launch_bounds__(256) void build_kernel(
    const int* __restrict__ ei, const float* __restrict__ ew,
    const int* __restrict__ mask,
    const float* __restrict__ W1, const float* __restrict__ W2,
    const float* __restrict__ W3,
    int* __restrict__ cursor, unsigned int* __restrict__ bkt,
    _Float16* __restrict__ Wt1, _Float16* __restrict__ Wt2,
    _Float16* __restrict__ Wt3,
    int* __restrict__ vlist, int* __restrict__ validN)
{
    __shared__ int sums[256];
    __shared__ int smask[NNODE];       // 16 KB (edge blocks only)
    const int blk = blockIdx.x;
    const int t   = threadIdx.x;

    if (blk < 2048) {
        // bkt entry = (fp16bits(w) << 16) | raw_u  (u < 4096 fits 12 bits)
        const int ebeg = blk * 512;                // 512 edges, same batch
        const int b    = ebeg >> 16;
        const int e    = (ebeg & (NEDGE - 1)) + t * 2;
        const int mrow = b * NNODE;

        const int* mb = mask + mrow;
        #pragma unroll
        for (int i = 0; i < 16; ++i) smask[t + i * 256] = mb[t + i * 256];
        __syncthreads();

        const int* eib = ei + (size_t)b * 2 * NEDGE;
        const int2 u2 = *(const int2*)&eib[e];
        const int2 v2 = *(const int2*)&eib[NEDGE + e];
        const float2 w2 = *(const float2*)&ew[(size_t)b * NEDGE + e];
        if (smask[u2.x] != 0 && smask[v2.x] != 0) {
            const unsigned short wb = __builtin_bit_cast(unsigned short, (_Float16)w2.x);
            const int pos = atomicAdd(&cursor[mrow + v2.x], 1);
            if (pos < DCAP)
                bkt[(size_t)(mrow + v2.x) * DCAP + pos] = ((unsigned)wb << 16) | (unsigned)u2.x;
        }
        if (smask[u2.y] != 0 && smask[v2.y] != 0) {
            const unsigned short wb = __builtin_bit_cast(unsigned short, (_Float16)w2.y);
            const int pos = atomicAdd(&cursor[mrow + v2.y], 1);
            if (pos < DCAP)
                bkt[(size_t)(mrow + v2.y) * DCAP + pos] = ((unsigned)wb << 16) | (unsigned)u2.y;
        }
    } else if (blk < 2560) {
        const int i = (blk - 2048) * 256 + t;      // [0, 131072)
        if (i < 32768) {
            int k = i >> 8, n = i & 255;
            Wt1[n * 128 + k] = (_Float16)W1[i];
        } else if (i < 98304) {
            int j = i - 32768;
            int k = j >> 8, n = j & 255;
            Wt2[n * 256 + k] = (_Float16)W2[j];
        } else {
            int j = i - 98304;
            int k = j >> 7, n = j & 127;
            Wt3[n * 256 + k] = (_Float16)W3[j];
        }
    } else {
        // per-batch node compaction
        const int b = blk - 2560;
        const int* mb = mask + b * NNODE;
        for (int i = t; i < CAP; i += 256) vlist[b * CAP + i] = 0;

        int loc[16]; int s = 0;
        #pragma unroll
        for (int i = 0; i < 16; ++i) { loc[i] = (mb[t * 16 + i] != 0); s += loc[i]; }
        sums[t] = s;
        __syncthreads();
        for (int off = 1; off < 256; off <<= 1) {
            int v = (t >= off) ? sums[t - off] : 0;
            __syncthreads();
            sums[t] += v;
            __syncthreads();
        }
        int run = (t == 0) ? 0 : sums[t - 1];
        #pragma unroll
        for (int i = 0; i < 16; ++i) {
            const int n = t * 16 + i;
            if (loc[i]) {
                if (run < CAP) vlist[b * CAP + run] = n;
                ++run;
            }
        }
        if (t == 255) validN[b] = run;
    }
}

// ---------------- standalone gathers: 1 slot/wave, TLP hides latency --------
// 38912 waves (152/CU). Bucket chunks loaded as uint4 pairs (32 B, aligned:
// bucket base 256 B, i multiple of 8) — was 8 scalar loads + addr calc.

__global__ __launch_bounds__(256) void gather_x(
    const int* __restrict__ cursor, const unsigned int* __restrict__ bkt,
    const float* __restrict__ X,       // [ROWS, 128] f32 (input)
    const int* __restrict__ vlist, const int* __restrict__ validN,
    _Float16* __restrict__ AggX)       // [PM, 128] compact
{
    constexpr int NU = CAP / 4;        // 608
    const int lane = threadIdx.x & 63;
    const int wave = threadIdx.x >> 6;
    const int xcd  = blockIdx.x & 7;
    const int jj   = blockIdx.x >> 3;
    const int batch = 2 * xcd + (jj >= NU);
    const int unit  = (jj >= NU) ? jj - NU : jj;

    const int j = unit * 4 + wave;
    if (j >= validN[batch]) return;
    const int mrow = batch * NNODE;
    const int v = vlist[batch * CAP + j];
    int deg = cursor[mrow + v];
    deg = deg > DCAP ? DCAP : deg;
    const unsigned* bk = bkt + (size_t)(mrow + v) * DCAP;
    const float* Xb = X + (size_t)mrow * 128 + lane * 2;

    float a0 = 0.0f, a1 = 0.0f;
    for (int i = 0; i < deg; i += 8) {
        const int cnt = deg - i;
        const uint4 q0 = *(const uint4*)&bk[i];
        const uint4 q1 = *(const uint4*)&bk[i + 4];
        const unsigned pk[8] = {q0.x, q0.y, q0.z, q0.w, q1.x, q1.y, q1.z, q1.w};
        float wj[8]; float2 xv[8];
        #pragma unroll
        for (int t = 0; t < 8; ++t) {
            const bool ok = (t < cnt);
            const unsigned u = pk[t] & 0xFFFu;           // < 4096: in-batch
            wj[t] = ok ? (float)__builtin_bit_cast(_Float16, (unsigned short)(pk[t] >> 16)) : 0.0f;
            xv[t] = *(const float2*)(Xb + (size_t)u * 128);
        }
        #pragma unroll
        for (int t = 0; t < 8; ++t) { a0 += wj[t] * xv[t].x; a1 += wj[t] * xv[t].y; }
    }
    half2v o = {(_Float16)a0, (_Float16)a1};
    *(half2v*)&AggX[(size_t)(batch * CAP + j) * 128 + lane * 2] = o;
}

__global__ __launch_bounds__(256) void gather_agg(
    const int* __restrict__ cursor, const unsigned int* __restrict__ bkt,
    const _Float16* __restrict__ Ac,   // [ROWS, 256] full layout
    const int* __restrict__ vlist, const int* __restrict__ validN,
    _Float16* __restrict__ AggA)       // [PM, 256] compact
{
    constexpr int NU = CAP / 4;
    const int lane = threadIdx.x & 63;
    const int wave = threadIdx.x >> 6;
    const int xcd  = blockIdx.x & 7;
    const int jj   = blockIdx.x >> 3;
    const int batch = 2 * xcd + (jj >= NU);
    const int unit  = (jj >= NU) ? jj - NU : jj;

    const int j = unit * 4 + wave;
    if (j >= validN[batch]) return;
    const int mrow = batch * NNODE;
    const int v = vlist[batch * CAP + j];
    int deg = cursor[mrow + v];
    deg = deg > DCAP ? DCAP : deg;
    const unsigned* bk = bkt + (size_t)(mrow + v) * DCAP;
    const _Float16* Ab = Ac + (size_t)mrow * 256 + lane * 4;

    float a0 = 0.0f, a1 = 0.0f, a2 = 0.0f, a3 = 0.0f;
    for (int i = 0; i < deg; i += 8) {
        const int cnt = deg - i;
        const uint4 q0 = *(const uint4*)&bk[i];
        const uint4 q1 = *(const uint4*)&bk[i + 4];
        const unsigned pk[8] = {q0.x, q0.y, q0.z, q0.w, q1.x, q1.y, q1.z, q1.w};
        float wj[8]; half4v hv[8];
        #pragma unroll
        for (int t = 0; t < 8; ++t) {
            const bool ok = (t < cnt);
            const unsigned u = pk[t] & 0xFFFu;           // valid u: Ac row written
            wj[t] = ok ? (float)__builtin_bit_cast(_Float16, (unsigned short)(pk[t] >> 16)) : 0.0f;
            hv[t] = *(const half4v*)(Ab + (size_t)u * 256);
        }
        #pragma unroll
        for (int t = 0; t < 8; ++t) {
            a0 += wj[t] * (float)hv[t][0];
            a1 += wj[t] * (float)hv[t][1];
            a2 += wj[t] * (float)hv[t][2];
            a3 += wj[t] * (float)hv[t][3];
        }
    }
    half4v o = {(_Float16)a0, (_Float16)a1, (_Float16)a2, (_Float16)a3};
    *(half4v*)&AggA[(size_t)(batch * CAP + j) * 256 + lane * 4] = o;
}

// ---------------- GEMM layer 1: AggX @ W1 -> relu+b1 -> scatter Ac ---------
__global__ __launch_bounds__(256, 3) void gemm1_kernel(
    const _Float16* __restrict__ Xc,   // AggX [PM, 128] compact
    const int* __restrict__ vlist, const int* __restrict__ validN,
    const _Float16* __restrict__ Wt,   // [256, 128]
    const float* __restrict__ bias,    // b1
    _Float16* __restrict__ Ac)         // [ROWS, 256] full layout
{
    constexpr int K = 128, NW = 64, NI = 4, RST = 72;
    constexpr int NPAN = 4;
    constexpr int NCH  = CAP / 64;     // 38
    constexpr int ASZ  = (NPAN * 2048) > (4 * 16 * RST) ? (NPAN * 2048) : (4 * 16 * RST);
    __shared__ _Float16 A16[ASZ];      // 16 KB, reused for store restage
    __shared__ int s_v[64];

    const int tid  = threadIdx.x;
    const int lane = tid & 63;
    const int wave = tid >> 6;
    const int quad = lane >> 4;
    const int l15  = lane & 15;

    const int xcd  = blockIdx.x & 7;
    const int j    = blockIdx.x >> 3;          // [0, 2*NCH)
    const int batch = 2 * xcd + (j >= NCH);
    const int tile  = (j >= NCH) ? j - NCH : j;
    const int vN   = validN[batch];
    if (tile * 64 >= vN) return;
    const int mrow = batch * NNODE;
    const size_t bm = (size_t)batch * CAP + (size_t)tile * 64;

    if (tid < 64) {
        const int slot = tile * 64 + tid;
        s_v[tid] = (slot < vN) ? vlist[batch * CAP + slot] : 0;
    }
    const int srow = tid >> 2;                 // 0..63
    const int sch  = (tid & 3) * 8;
    #pragma unroll
    for (int pp = 0; pp < NPAN; ++pp)
        __builtin_amdgcn_global_load_lds(
            GP(Xc + (bm + srow) * K + pp * 32 + sch),
            LP(A16 + pp * 2048 + tid * 8), 16, 0, 0);
    __syncthreads();

    f32x4 acc[4][NI];
    #pragma unroll
    for (int mi = 0; mi < 4; ++mi)
        #pragma unroll
        for (int ni = 0; ni < NI; ++ni) acc[mi][ni] = (f32x4)0.0f;

    const _Float16* ap = A16 + l15 * 32 + quad * 8;
    const _Float16* wp = Wt + (size_t)(wave * NW + l15) * K + quad * 8;

    #pragma unroll
    for (int pp = 0; pp < NPAN; ++pp) {
        half8 af[4], bf[NI];
        #pragma unroll
        for (int mi = 0; mi < 4; ++mi)
            af[mi] = *(const half8*)(ap + pp * 2048 + mi * 16 * 32);
        #pragma unroll
        for (int ni = 0; ni < NI; ++ni)
            bf[ni] = *(const half8*)(wp + (size_t)ni * 16 * K + pp * 32);
        #pragma unroll
        for (int mi = 0; mi < 4; ++mi)
            #pragma unroll
            for (int ni = 0; ni < NI; ++ni)
                acc[mi][ni] = __builtin_amdgcn_mfma_f32_16x16x32_f16(
                    bf[ni], af[mi], acc[mi][ni], 0, 0, 0);   // swapped
    }
    __syncthreads();   // A16 free for store restage

    _Float16* stg = A16 + wave * 16 * RST;
    const int rr = lane >> 2;
    const int c0 = lane & 3;
    #pragma unroll
    for (int mi = 0; mi < 4; ++mi) {
        #pragma unroll
        for (int ni = 0; ni < NI; ++ni) {
            f32x4 v = acc[mi][ni];
            const f32x4 bv = *(const f32x4*)&bias[wave * NW + ni * 16 + quad * 4];
            half4v o;
            #pragma unroll
            for (int r = 0; r < 4; ++r) o[r] = (_Float16)fmaxf(v[r] + bv[r], 0.0f);
            *(half4v*)&stg[l15 * RST + ni * 16 + quad * 4] = o;
        }
        const int slot = tile * 64 + mi * 16 + rr;
        if (slot < vN) {
            const int vs = s_v[mi * 16 + rr];
            _Float16* hp2 = &Ac[((size_t)mrow + vs) * 256 + wave * NW];
            #pragma unroll
            for (int c = 0; c < NI / 2; ++c) {
                const int ch = (c0 + 4 * c) * 8;
                half8 v = *(const half8*)&stg[rr * RST + ch];
                *(half8*)(hp2 + ch) = v;
            }
        }
    }
}

// ---------------- GEMM layers 2+3: AggA @ W2 -> relu -> @ W3 -> scatter H3 --
__global__ __launch_bounds__(256, 3) void gemm23_kernel(
    const _Float16* __restrict__ Xc,   // AggA [PM, 256] compact
    const int* __restrict__ vlist, const int* __restrict__ validN,
    const _Float16* __restrict__ Wt2,  // [256, 256]
    const _Float16* __restrict__ Wt3,  // [128, 256]
    const float* __restrict__ b2,
    _Float16* __restrict__ H3)         // [ROWS, 128] full layout
{
    constexpr int K    = 256;
    constexpr int NPAN = 8;
    constexpr int NCH  = CAP / 64;     // 38
    __shared__ _Float16 A16[NPAN * 2048];   // 32 KB, reused 3x
    __shared__ int s_v[64];

    const int tid  = threadIdx.x;
    const int lane = tid & 63;
    const int wave = tid >> 6;
    const int quad = lane >> 4;
    const int l15  = lane & 15;

    const int xcd  = blockIdx.x & 7;
    const int j    = blockIdx.x >> 3;
    const int batch = 2 * xcd + (j >= NCH);
    const int tile  = (j >= NCH) ? j - NCH : j;
    const int vN   = validN[batch];
    if (tile * 64 >= vN) return;
    const int mrow = batch * NNODE;
    const size_t bm = (size_t)batch * CAP + (size_t)tile * 64;

    if (tid < 64) {
        const int slot = tile * 64 + tid;
        s_v[tid] = (slot < vN) ? vlist[batch * CAP + slot] : 0;
    }
    const int srow = tid >> 2;
    const int sch  = (tid & 3) * 8;
    #pragma unroll
    for (int pp = 0; pp < NPAN; ++pp)
        __builtin_amdgcn_global_load_lds(
            GP(Xc + (bm + srow) * K + pp * 32 + sch),
            LP(A16 + pp * 2048 + tid * 8), 16, 0, 0);
    __syncthreads();

    // ---- phase 1: layer-2 matmul (64 cols/wave, NI=4) ----
    f32x4 acc[4][4];
    #pragma unroll
    for (int mi = 0; mi < 4; ++mi)
        #pragma unroll
        for (int ni = 0; ni < 4; ++ni) acc[mi][ni] = (f32x4)0.0f;

    const _Float16* ap = A16 + l15 * 32 + quad * 8;
    const _Float16* wp = Wt2 + (size_t)(wave * 64 + l15) * K + quad * 8;

    #pragma unroll
    for (int pp = 0; pp < NPAN; ++pp) {
        half8 af[4], bf[4];
        #pragma unroll
        for (int mi = 0; mi < 4; ++mi)
            af[mi] = *(const half8*)(ap + pp * 2048 + mi * 16 * 32);
        #pragma unroll
        for (int ni = 0; ni < 4; ++ni)
            bf[ni] = *(const half8*)(wp + (size_t)ni * 16 * K + pp * 32);
        #pragma unroll
        for (int mi = 0; mi < 4; ++mi)
            #pragma unroll
            for (int ni = 0; ni < 4; ++ni)
                acc[mi][ni] = __builtin_amdgcn_mfma_f32_16x16x32_f16(
                    bf[ni], af[mi], acc[mi][ni], 0, 0, 0);
    }
    __syncthreads();   // all waves done reading AggA panels

    // ---- epilogue 1: relu(acc + b2) -> A16 panel layout [pp][row][32] ----
    #pragma unroll
    for (int mi = 0; mi < 4; ++mi) {
        const int row = mi * 16 + l15;
        #pragma unroll
        for (int ni = 0; ni < 4; ++ni) {
            const int col = wave * 64 + ni * 16 + quad * 4;
            const f32x4 bv = *(const f32x4*)&b2[col];
            f32x4 v = acc[mi][ni];
            half4v o;
            #pragma unroll
            for (int r = 0; r < 4; ++r) o[r] = (_Float16)fmaxf(v[r] + bv[r], 0.0f);
            *(half4v*)&A16[(col >> 5) * 2048 + row * 32 + (col & 31)] = o;
        }
    }
    __syncthreads();

    // ---- phase 2: layer-3 matmul from LDS (32 cols/wave, NI=2) ----
    f32x4 acc2[4][2];
    #pragma unroll
    for (int mi = 0; mi < 4; ++mi)
        #pragma unroll
        for (int ni = 0; ni < 2; ++ni) acc2[mi][ni] = (f32x4)0.0f;

    const _Float16* wp3 = Wt3 + (size_t)(wave * 32 + l15) * K + quad * 8;
    #pragma unroll
    for (int pp = 0; pp < NPAN; ++pp) {
        half8 af[4], bf[2];
        #pragma unroll
        for (int mi = 0; mi < 4; ++mi)
            af[mi] = *(const half8*)(ap + pp * 2048 + mi * 16 * 32);
        #pragma unroll
        for (int ni = 0; ni < 2; ++ni)
            bf[ni] = *(const half8*)(wp3 + (size_t)ni * 16 * K + pp * 32);
        #pragma unroll
        for (int mi = 0; mi < 4; ++mi)
            #pragma unroll
            for (int ni = 0; ni < 2; ++ni)
                acc2[mi][ni] = __builtin_amdgcn_mfma_f32_16x16x32_f16(
                    bf[ni], af[mi], acc2[mi][ni], 0, 0, 0);
    }
    __syncthreads();   // A16 free for store restage

    constexpr int RST = 40;            // 32 + 8 pad
    _Float16* stg = A16 + wave * 16 * RST;
    const int rr = lane >> 2;
    const int c0 = lane & 3;
    #pragma unroll
    for (int mi = 0; mi < 4; ++mi) {
        #pragma unroll
        for (int ni = 0; ni < 2; ++ni) {
            f32x4 v = acc2[mi][ni];
            half4v o;
            #pragma unroll
            for (int r = 0; r < 4; ++r) o[r] = (_Float16)v[r];
            *(half4v*)&stg[l15 * RST + ni * 16 + quad * 4] = o;
        }
        const int slot = tile * 64 + mi * 16 + rr;
        if (slot < vN) {
            const int vs = s_v[mi * 16 + rr];
            _Float16* hp2 = &H3[((size_t)mrow + vs) * 128 + wave * 32];
            const int ch = c0 * 8;
            half8 v = *(const half8*)&stg[rr * RST + ch];
            *(half8*)(hp2 + ch) = v;
        }
    }
}

// ---------------- final gather (1 node/wave, static XCD-affine) -------------
__global__ __launch_bounds__(256) void gather_final(
    const int* __restrict__ cursor, const unsigned int* __restrict__ bkt,
    const _Float16* __restrict__ H3,   // [ROWS, 128]
    const int* __restrict__ mask, const float* __restrict__ bias,
    float* __restrict__ OUT)           // [ROWS, 128]
{
    constexpr int NU = NNODE / 4;      // 1024 units (4 nodes) per batch
    const int lane = threadIdx.x & 63;
    const int wave = threadIdx.x >> 6;

    const int xcd  = blockIdx.x & 7;
    const int jj   = blockIdx.x >> 3;
    const int batch = 2 * xcd + (jj >= NU);
    const int unit  = (jj >= NU) ? jj - NU : jj;

    const int n = unit * 4 + wave;
    const int mrow = batch * NNODE + n;

    float acc[2] = {};
    if (mask[mrow] != 0) {
        int deg = cursor[mrow];
        deg = deg > DCAP ? DCAP : deg;
        const unsigned* bk = bkt + (size_t)mrow * DCAP;
        const _Float16* Hb = H3 + (size_t)batch * NNODE * 128 + lane * 2;

        for (int i = 0; i < deg; i += 8) {
            const int cnt = deg - i;
            const uint4 q0 = *(const uint4*)&bk[i];
            const uint4 q1 = *(const uint4*)&bk[i + 4];
            const unsigned pk[8] = {q0.x, q0.y, q0.z, q0.w, q1.x, q1.y, q1.z, q1.w};
            float wj[8]; const _Float16* hp[8];
            #pragma unroll
            for (int t = 0; t < 8; ++t) {
                const bool ok = (t < cnt);
                const unsigned u = pk[t] & 0xFFFu;
                wj[t] = ok ? (float)__builtin_bit_cast(_Float16, (unsigned short)(pk[t] >> 16)) : 0.0f;
                hp[t] = Hb + (size_t)u * 128;
            }
            half2v hv[8];
            #pragma unroll
            for (int t = 0; t < 8; ++t) hv[t] = *(const half2v*)hp[t];
            #pragma unroll
            for (int t = 0; t < 8; ++t)
                #pragma unroll
                for (int c = 0; c < 2; ++c) acc[c] += wj[t] * (float)hv[t][c];
        }
        #pragma unroll
        for (int c = 0; c < 2; ++c)
            acc[c] = fmaxf(acc[c] + bias[lane * 2 + c], 0.0f);
    }
    f32x2 o = {acc[0], acc[1]};
    *(f32x2*)&OUT[(size_t)mrow * 128 + lane * 2] = o;
}

extern "C" void kernel_launch(void* const* d_in, const int* in_sizes, int n_in,
                              void* d_out, int out_size, void* d_ws, size_t ws_size,
                              hipStream_t stream) {
    const float* x    = (const float*)d_in[0];
    const int*   ei   = (const int*)  d_in[1];
    const float* ew   = (const float*)d_in[2];
    const int*   mask = (const int*)  d_in[3];
    const float* W1   = (const float*)d_in[4];
    const float* b1   = (const float*)d_in[5];
    const float* W2   = (const float*)d_in[6];
    const float* b2   = (const float*)d_in[7];
    const float* W3   = (const float*)d_in[8];
    const float* b3   = (const float*)d_in[9];
    float* out = (float*)d_out;

    // Workspace layout (~95 MB):
    char* ws = (char*)d_ws;
    _Float16* Ac   = (_Float16*)(ws);                      // 32 MB [ROWS,256] full
    _Float16* H3   = (_Float16*)(ws + (32u << 20));        // 16 MB [ROWS,128] full
    unsigned int* bkt = (unsigned int*)(ws + (48u << 20)); // 16 MB [ROWS,DCAP]
    _Float16* AggX = (_Float16*)(ws + (64u << 20));        // 10 MB [PM,128] compact
    _Float16* AggA = (_Float16*)(ws + (74u << 20));        // 20 MB [PM,256] compact
    _Float16* Wt1  = (_Float16*)(ws + (94u << 20));        // 64 KB
    _Float16* Wt2  = Wt1 + 128 * 256;                      // 128 KB
    _Float16* Wt3  = Wt2 + 256 * 256;                      // 64 KB
    int* cursor    = (int*)(Wt3 + 256 * 128);              // 256 KB (degrees)
    int* vlist     = cursor + ROWS;                        // 152 KB
    int* validN    = vlist + PM;

    const dim3 blk(256);

    // ---- 1. zero degree cursors ----
    hipMemsetAsync(cursor, 0, (size_t)ROWS * sizeof(int), stream);

    // ---- 2. build: buckets (LDS mask, 2 edges/thread) + W casts + compact --
    build_kernel<<<2576, blk, 0, stream>>>(ei, ew, mask, W1, W2, W3,
                                           cursor, bkt, Wt1, Wt2, Wt3,
                                           vlist, validN);

    const int gemmBlocks = PM / 64;      // 608
    const int aggBlocks  = PM / 4;       // 9728
    const int finBlocks  = ROWS / 4;     // 16384

    // ---- 3. layer 1: standalone aggregation (agg-first linearity), GEMM ----
    gather_x<<<aggBlocks, blk, 0, stream>>>(cursor, bkt, x, vlist, validN, AggX);
    gemm1_kernel<<<gemmBlocks, blk, 0, stream>>>(AggX, vlist, validN, Wt1, b1, Ac);

    // ---- 4. layers 2+3: standalone aggregation, fused 2-layer GEMM ----
    gather_agg<<<aggBlocks, blk, 0, stream>>>(cursor, bkt, Ac, vlist, validN, AggA);
    gemm23_kernel<<<gemmBlocks, blk, 0, stream>>>(AggA, vlist, validN, Wt2, Wt3, b2, H3);

    // ---- 5. layer-3 aggregation + bias/relu/mask ----
    gather_final<<<finBlocks, blk, 0, stream>>>(cursor, bkt, H3, mask, b3, out);
}